// Round 3
// baseline (365.421 us; speedup 1.0000x reference)
//
#include <hip/hip_runtime.h>
#include <hip/hip_bf16.h>
#include <math.h>

#define Bz 4
#define Nn 512
#define Hh 512
#define NHh 8
#define HDd 64
#define DEe 64
#define DFFf 2048
#define EPSs 1e-5f

typedef __attribute__((ext_vector_type(8))) short bf16x8;
typedef __attribute__((ext_vector_type(4))) float f32x4;

__device__ inline short f2bf(float x) {
    unsigned u = __builtin_bit_cast(unsigned, x);
    unsigned r = (u + 0x7FFFu + ((u >> 16) & 1u)) >> 16;
    return (short)r;
}

// ---------------------------------------------------------------------------
// Distance-embedding means
// dq_emb[b,i,d] = (1/N) sum_n emb[idx[b,i,n]][d]   (row mean, axis=2)
// dk_emb[b,j,d] = (1/N) sum_i emb[idx[b,i,j]][d]   (col mean, axis=1)
// ---------------------------------------------------------------------------
__global__ __launch_bounds__(256) void dmean_row_kernel(
    const float* __restrict__ dist, const float* __restrict__ emb,
    float* __restrict__ dqe)
{
    int bi = blockIdx.x;              // b*N + i
    int d = threadIdx.x & 63;
    int g = threadIdx.x >> 6;
    const float* drow = dist + (size_t)bi * Nn;
    float acc = 0.f;
    for (int n = g; n < Nn; n += 4) {
        int id = (int)drow[n];
        id = min(max(id, 0), 200);
        acc += emb[id * DEe + d];
    }
    __shared__ float red[4][64];
    red[g][d] = acc;
    __syncthreads();
    if (g == 0) {
        float s = red[0][d] + red[1][d] + red[2][d] + red[3][d];
        dqe[(size_t)bi * DEe + d] = s * (1.0f / Nn);
    }
}

__global__ __launch_bounds__(256) void dmean_col_kernel(
    const float* __restrict__ dist, const float* __restrict__ emb,
    float* __restrict__ dke)
{
    int bj = blockIdx.x;              // b*N + j
    int b = bj >> 9, j = bj & 511;
    int d = threadIdx.x & 63;
    int g = threadIdx.x >> 6;
    float acc = 0.f;
    for (int i = g; i < Nn; i += 4) {
        int id = (int)dist[((size_t)(b * Nn + i)) * Nn + j];
        id = min(max(id, 0), 200);
        acc += emb[id * DEe + d];
    }
    __shared__ float red[4][64];
    red[g][d] = acc;
    __syncthreads();
    if (g == 0) {
        float s = red[0][d] + red[1][d] + red[2][d] + red[3][d];
        dke[(size_t)bj * DEe + d] = s * (1.0f / Nn);
    }
}

// ---------------------------------------------------------------------------
// bf16 MFMA GEMM: C[M][Nc] = act( A[M][K] @ W[Nc][K]^T + bias + (R?) )
// A, W row-major f32 (K contiguous), converted to bf16 during LDS staging.
// 64x64 block tile, 4 waves (2x2), each wave 32x32 via 2x2 mfma 16x16x32.
// LDS XOR-swizzled: short index sidx(r,c) = r*64 + (c ^ ((r&7)<<3)).
// Fragment layouts (gfx950, HW-verified):
//   A: row = lane&15, k = (lane>>4)*8 + i  (8 contiguous bf16)
//   B: col = lane&15, k = (lane>>4)*8 + i  (= W row, contiguous)
//   D: col = lane&15, row = (lane>>4)*4 + reg
// ---------------------------------------------------------------------------
template<bool RELU, bool RES>
__global__ __launch_bounds__(256) void mgemm_kernel(
    const float* __restrict__ A, const float* __restrict__ W,
    const float* __restrict__ bias, const float* __restrict__ Rr,
    float* __restrict__ C, int M, int Nc, int K)
{
    __shared__ short As[64 * 64];
    __shared__ short Ws[64 * 64];
    int t = threadIdx.x;
    int lane = t & 63;
    int wid = t >> 6;                 // wave 0..3
    int wm = wid >> 1, wn = wid & 1;  // 2x2 wave grid
    int m0 = blockIdx.y * 64, n0 = blockIdx.x * 64;

    // staging: thread t -> row lr = t>>2, cols c0..c0+15 (c0 = (t&3)*16)
    int lr = t >> 2;
    int c0 = (t & 3) * 16;
    int sw = (lr & 7) << 3;           // short-index swizzle for this row

    const float* Arow = A + (size_t)(m0 + lr) * K + c0;
    const float* Wrow = W + (size_t)(n0 + lr) * K + c0;

    f32x4 acc[2][2] = {};

    for (int kt = 0; kt < K; kt += 64) {
        // ---- stage A tile ----
        {
            float4 v0 = *(const float4*)(Arow + kt);
            float4 v1 = *(const float4*)(Arow + kt + 4);
            float4 v2 = *(const float4*)(Arow + kt + 8);
            float4 v3 = *(const float4*)(Arow + kt + 12);
            bf16x8 p0 = {f2bf(v0.x), f2bf(v0.y), f2bf(v0.z), f2bf(v0.w),
                         f2bf(v1.x), f2bf(v1.y), f2bf(v1.z), f2bf(v1.w)};
            bf16x8 p1 = {f2bf(v2.x), f2bf(v2.y), f2bf(v2.z), f2bf(v2.w),
                         f2bf(v3.x), f2bf(v3.y), f2bf(v3.z), f2bf(v3.w)};
            *(bf16x8*)&As[lr * 64 + ((c0 + 0) ^ sw)] = p0;
            *(bf16x8*)&As[lr * 64 + ((c0 + 8) ^ sw)] = p1;
        }
        // ---- stage W tile ----
        {
            float4 v0 = *(const float4*)(Wrow + kt);
            float4 v1 = *(const float4*)(Wrow + kt + 4);
            float4 v2 = *(const float4*)(Wrow + kt + 8);
            float4 v3 = *(const float4*)(Wrow + kt + 12);
            bf16x8 p0 = {f2bf(v0.x), f2bf(v0.y), f2bf(v0.z), f2bf(v0.w),
                         f2bf(v1.x), f2bf(v1.y), f2bf(v1.z), f2bf(v1.w)};
            bf16x8 p1 = {f2bf(v2.x), f2bf(v2.y), f2bf(v2.z), f2bf(v2.w),
                         f2bf(v3.x), f2bf(v3.y), f2bf(v3.z), f2bf(v3.w)};
            *(bf16x8*)&Ws[lr * 64 + ((c0 + 0) ^ sw)] = p0;
            *(bf16x8*)&Ws[lr * 64 + ((c0 + 8) ^ sw)] = p1;
        }
        __syncthreads();

        int kgrp = (lane >> 4) * 8;
#pragma unroll
        for (int kk = 0; kk < 64; kk += 32) {
            bf16x8 fa[2], fb[2];
            int ko = kk + kgrp;
#pragma unroll
            for (int mt = 0; mt < 2; ++mt) {
                int r = wm * 32 + mt * 16 + (lane & 15);
                fa[mt] = *(bf16x8*)&As[r * 64 + (ko ^ ((r & 7) << 3))];
            }
#pragma unroll
            for (int nt = 0; nt < 2; ++nt) {
                int r = wn * 32 + nt * 16 + (lane & 15);
                fb[nt] = *(bf16x8*)&Ws[r * 64 + (ko ^ ((r & 7) << 3))];
            }
#pragma unroll
            for (int mt = 0; mt < 2; ++mt)
#pragma unroll
                for (int nt = 0; nt < 2; ++nt)
                    acc[mt][nt] = __builtin_amdgcn_mfma_f32_16x16x32_bf16(
                        fa[mt], fb[nt], acc[mt][nt], 0, 0, 0);
        }
        __syncthreads();
    }

    // epilogue: D col = lane&15, row = (lane>>4)*4 + reg
    int cr = (lane >> 4) * 4;
    int cc = lane & 15;
#pragma unroll
    for (int mt = 0; mt < 2; ++mt) {
#pragma unroll
        for (int nt = 0; nt < 2; ++nt) {
            int col = n0 + wn * 32 + nt * 16 + cc;
            float bv = bias[col];
#pragma unroll
            for (int r = 0; r < 4; ++r) {
                int row = m0 + wm * 32 + mt * 16 + cr + r;
                float o = acc[mt][nt][r] + bv;
                if (RES) o += Rr[(size_t)row * Nc + col];
                if (RELU) o = fmaxf(o, 0.f);
                C[(size_t)row * Nc + col] = o;
            }
        }
    }
}

// ---------------------------------------------------------------------------
// Attention: per (b, h, 16-row q-tile). Scores in LDS, masked softmax, S@V.
// Q/K/V layout: (B, N, H) with head h occupying cols [h*64, h*64+64).
// ---------------------------------------------------------------------------
#define QT 16
__global__ __launch_bounds__(256) void attn_kernel(
    const float* __restrict__ Qm, const float* __restrict__ Km,
    const float* __restrict__ Vm, const float* __restrict__ mask,
    float* __restrict__ AO)
{
    __shared__ float Qs[QT][68];
    __shared__ float KVs[64][68];
    __shared__ float S[QT][516];
    int i0 = blockIdx.x * QT;
    int h = blockIdx.y;
    int b = blockIdx.z;
    int t = threadIdx.x;
    int qi = t >> 4;      // 0..15
    int sl = t & 15;      // 0..15

    // load Q tile: 16*64 floats = 256 float4, one per thread
    {
        int r = t >> 4, c = (t & 15) * 4;
        *(float4*)&Qs[r][c] =
            *(const float4*)&Qm[((size_t)(b * Nn + i0 + r)) * Hh + h * HDd + c];
    }
    __syncthreads();
    // hoist this thread's q row into registers
    float qreg[HDd];
#pragma unroll
    for (int d4 = 0; d4 < HDd; d4 += 4) {
        float4 qv = *(const float4*)&Qs[qi][d4];
        qreg[d4] = qv.x; qreg[d4 + 1] = qv.y; qreg[d4 + 2] = qv.z; qreg[d4 + 3] = qv.w;
    }
    const float scale = 0.125f;   // 1/sqrt(64)

    // phase 1: scores
    for (int kc = 0; kc < Nn / 64; ++kc) {
        __syncthreads();
        for (int l = t; l < 64 * (HDd / 4); l += 256) {
            int r = l >> 4, c = (l & 15) * 4;
            *(float4*)&KVs[r][c] =
                *(const float4*)&Km[((size_t)(b * Nn + kc * 64 + r)) * Hh + h * HDd + c];
        }
        __syncthreads();
#pragma unroll
        for (int c = 0; c < 4; ++c) {
            int kj = sl + c * 16;
            float acc = 0.f;
#pragma unroll
            for (int d4 = 0; d4 < HDd; d4 += 4) {
                float4 kv = *(const float4*)&KVs[kj][d4];
                acc += qreg[d4] * kv.x + qreg[d4 + 1] * kv.y +
                       qreg[d4 + 2] * kv.z + qreg[d4 + 3] * kv.w;
            }
            int j = kc * 64 + kj;
            float mv = mask[((size_t)(b * Nn + i0 + qi)) * Nn + j];
            S[qi][j] = (mv == 0.0f) ? -INFINITY : acc * scale;
        }
    }
    __syncthreads();

    // phase 2: softmax over row qi (16 threads per row)
    float mx = -INFINITY;
    for (int j = sl; j < Nn; j += 16) mx = fmaxf(mx, S[qi][j]);
#pragma unroll
    for (int o = 1; o < 16; o <<= 1) mx = fmaxf(mx, __shfl_xor(mx, o));
    float sum = 0.f;
    for (int j = sl; j < Nn; j += 16) {
        float e = __expf(S[qi][j] - mx);
        S[qi][j] = e;
        sum += e;
    }
#pragma unroll
    for (int o = 1; o < 16; o <<= 1) sum += __shfl_xor(sum, o);
    float inv = 1.0f / sum;
    for (int j = sl; j < Nn; j += 16) S[qi][j] *= inv;

    // phase 3: AO tile = S @ V
    float acc[4] = {};
    int d0 = sl * 4;
    for (int kc = 0; kc < Nn / 64; ++kc) {
        __syncthreads();
        for (int l = t; l < 64 * (HDd / 4); l += 256) {
            int r = l >> 4, c = (l & 15) * 4;
            *(float4*)&KVs[r][c] =
                *(const float4*)&Vm[((size_t)(b * Nn + kc * 64 + r)) * Hh + h * HDd + c];
        }
        __syncthreads();
#pragma unroll
        for (int k = 0; k < 64; ++k) {
            float s = S[qi][kc * 64 + k];
            float4 vv = *(const float4*)&KVs[k][d0];
            acc[0] += s * vv.x; acc[1] += s * vv.y;
            acc[2] += s * vv.z; acc[3] += s * vv.w;
        }
    }
    float4 ov = {acc[0], acc[1], acc[2], acc[3]};
    *(float4*)&AO[((size_t)(b * Nn + i0 + qi)) * Hh + h * HDd + d0] = ov;
}

// ---------------------------------------------------------------------------
// GRU elementwise:  u = (1-z)*n + z*msg
// ---------------------------------------------------------------------------
__global__ __launch_bounds__(256) void gru_kernel(
    const float* __restrict__ gx, const float* __restrict__ gh,
    const float* __restrict__ msg, float* __restrict__ u)
{
    int i = blockIdx.x * 256 + threadIdx.x;
    int row = i >> 9, col = i & 511;
    const float* gxr = gx + (size_t)row * (3 * Hh);
    const float* ghr = gh + (size_t)row * (3 * Hh);
    float xr = gxr[col], xz = gxr[col + 512], xn = gxr[col + 1024];
    float hr = ghr[col], hz = ghr[col + 512], hn = ghr[col + 1024];
    float r = 1.f / (1.f + __expf(-(xr + hr)));
    float z = 1.f / (1.f + __expf(-(xz + hz)));
    float n = tanhf(xn + r * hn);
    u[i] = (1.f - z) * n + z * msg[i];
}

// ---------------------------------------------------------------------------
// LayerNorm over rows of 512
// ---------------------------------------------------------------------------
__global__ __launch_bounds__(256) void ln_kernel(
    const float* __restrict__ Y, const float* __restrict__ g,
    const float* __restrict__ be, float* __restrict__ out)
{
    int row = blockIdx.x, t = threadIdx.x;
    const float* yr = Y + (size_t)row * Hh;
    float v0 = yr[t], v1 = yr[t + 256];
    float s = v0 + v1, s2 = v0 * v0 + v1 * v1;
#pragma unroll
    for (int o = 1; o < 64; o <<= 1) {
        s += __shfl_xor(s, o);
        s2 += __shfl_xor(s2, o);
    }
    __shared__ float rs[4], rs2[4];
    int w = t >> 6;
    if ((t & 63) == 0) { rs[w] = s; rs2[w] = s2; }
    __syncthreads();
    float ts = rs[0] + rs[1] + rs[2] + rs[3];
    float ts2 = rs2[0] + rs2[1] + rs2[2] + rs2[3];
    float mu = ts * (1.0f / Hh);
    float var = ts2 * (1.0f / Hh) - mu * mu;
    float rstd = rsqrtf(var + EPSs);
    out[(size_t)row * Hh + t] = (v0 - mu) * rstd * g[t] + be[t];
    out[(size_t)row * Hh + t + 256] = (v1 - mu) * rstd * g[t + 256] + be[t + 256];
}

// ---------------------------------------------------------------------------
extern "C" void kernel_launch(void* const* d_in, const int* in_sizes, int n_in,
                              void* d_out, int out_size, void* d_ws, size_t ws_size,
                              hipStream_t stream) {
    const float* messages = (const float*)d_in[0];
    const float* dist     = (const float*)d_in[1];
    const float* mask     = (const float*)d_in[2];
    const float* emb      = (const float*)d_in[3];
    const float* Wdq = (const float*)d_in[4];  const float* bdq = (const float*)d_in[5];
    const float* Wdk = (const float*)d_in[6];  const float* bdk = (const float*)d_in[7];
    const float* Wq  = (const float*)d_in[8];  const float* bq  = (const float*)d_in[9];
    const float* Wk  = (const float*)d_in[10]; const float* bk  = (const float*)d_in[11];
    const float* Wv  = (const float*)d_in[12]; const float* bv  = (const float*)d_in[13];
    const float* Wo  = (const float*)d_in[14]; const float* bo  = (const float*)d_in[15];
    const float* W_ih = (const float*)d_in[16]; const float* b_ih = (const float*)d_in[17];
    const float* W_hh = (const float*)d_in[18]; const float* b_hh = (const float*)d_in[19];
    const float* W1  = (const float*)d_in[20]; const float* b1  = (const float*)d_in[21];
    const float* W2  = (const float*)d_in[22]; const float* b2  = (const float*)d_in[23];
    const float* g2  = (const float*)d_in[24]; const float* beta2 = (const float*)d_in[25];

    const int M = Bz * Nn;  // 2048

    float* w = (float*)d_ws;
    float* dqe = w;                         // 131072
    float* dke = dqe + 131072;              // 131072
    float* XQ  = dke + 131072;              // 1048576
    float* XK  = XQ + 1048576;              // 1048576
    float* Qb  = XK + 1048576;              // 1048576
    float* Kb  = Qb + 1048576;              // 1048576
    float* Vb  = Kb + 1048576;              // 1048576
    float* gx  = Vb + 1048576;              // 3145728
    float* gh  = gx + 3145728;              // 3145728
    // reuse (stream-serial, producers strictly after last consumers):
    float* AO  = XQ;   // XQ dead after Q GEMM
    float* ao  = XK;   // XK dead after K GEMM
    float* ub  = Qb;   // Q dead after attention
    float* f1  = gx;   // gx+gh (6.29M floats) dead after GRU; f1 needs 4.19M
    float* yb  = Kb;   // K dead after attention

    dim3 blk(256);

    dmean_row_kernel<<<M, blk, 0, stream>>>(dist, emb, dqe);
    dmean_col_kernel<<<M, blk, 0, stream>>>(dist, emb, dke);

    // XQ = messages + dqe @ Wdq^T + bdq ; XK = messages + dke @ Wdk^T + bdk
    mgemm_kernel<false, true><<<dim3(Hh / 64, M / 64), blk, 0, stream>>>(
        dqe, Wdq, bdq, messages, XQ, M, Hh, DEe);
    mgemm_kernel<false, true><<<dim3(Hh / 64, M / 64), blk, 0, stream>>>(
        dke, Wdk, bdk, messages, XK, M, Hh, DEe);

    // Q, K, V projections
    mgemm_kernel<false, false><<<dim3(Hh / 64, M / 64), blk, 0, stream>>>(
        XQ, Wq, bq, nullptr, Qb, M, Hh, Hh);
    mgemm_kernel<false, false><<<dim3(Hh / 64, M / 64), blk, 0, stream>>>(
        XK, Wk, bk, nullptr, Kb, M, Hh, Hh);
    mgemm_kernel<false, false><<<dim3(Hh / 64, M / 64), blk, 0, stream>>>(
        messages, Wv, bv, nullptr, Vb, M, Hh, Hh);

    // attention
    attn_kernel<<<dim3(Nn / QT, NHh, Bz), blk, 0, stream>>>(Qb, Kb, Vb, mask, AO);

    // output projection
    mgemm_kernel<false, false><<<dim3(Hh / 64, M / 64), blk, 0, stream>>>(
        AO, Wo, bo, nullptr, ao, M, Hh, Hh);

    // GRU gates
    mgemm_kernel<false, false><<<dim3(3 * Hh / 64, M / 64), blk, 0, stream>>>(
        ao, W_ih, b_ih, nullptr, gx, M, 3 * Hh, Hh);
    mgemm_kernel<false, false><<<dim3(3 * Hh / 64, M / 64), blk, 0, stream>>>(
        messages, W_hh, b_hh, nullptr, gh, M, 3 * Hh, Hh);
    gru_kernel<<<(M * Hh) / 256, blk, 0, stream>>>(gx, gh, messages, ub);

    // FFN
    mgemm_kernel<true, false><<<dim3(DFFf / 64, M / 64), blk, 0, stream>>>(
        ub, W1, b1, nullptr, f1, M, DFFf, Hh);
    mgemm_kernel<false, true><<<dim3(Hh / 64, M / 64), blk, 0, stream>>>(
        f1, W2, b2, ub, yb, M, Hh, DFFf);

    // LayerNorm -> out
    ln_kernel<<<M, blk, 0, stream>>>(yb, g2, beta2, (float*)d_out);
}

// Round 4
// 293.387 us; speedup vs baseline: 1.2455x; 1.2455x over previous
//
#include <hip/hip_runtime.h>
#include <hip/hip_bf16.h>
#include <math.h>

#define Bz 4
#define Nn 512
#define Hh 512
#define NHh 8
#define HDd 64
#define DEe 64
#define DFFf 2048
#define EPSs 1e-5f

typedef __attribute__((ext_vector_type(8))) short bf16x8;
typedef __attribute__((ext_vector_type(4))) short bf16x4;
typedef __attribute__((ext_vector_type(4))) float f32x4;

__device__ inline short f2bf(float x) {
    unsigned u = __builtin_bit_cast(unsigned, x);
    unsigned r = (u + 0x7FFFu + ((u >> 16) & 1u)) >> 16;
    return (short)r;
}

// ---------------------------------------------------------------------------
// Distance-embedding means
// ---------------------------------------------------------------------------
__global__ __launch_bounds__(256) void dmean_row_kernel(
    const float* __restrict__ dist, const float* __restrict__ emb,
    float* __restrict__ dqe)
{
    int bi = blockIdx.x;              // b*N + i
    int d = threadIdx.x & 63;
    int g = threadIdx.x >> 6;
    const float* drow = dist + (size_t)bi * Nn;
    float acc = 0.f;
    for (int n = g; n < Nn; n += 4) {
        int id = (int)drow[n];
        id = min(max(id, 0), 200);
        acc += emb[id * DEe + d];
    }
    __shared__ float red[4][64];
    red[g][d] = acc;
    __syncthreads();
    if (g == 0) {
        float s = red[0][d] + red[1][d] + red[2][d] + red[3][d];
        dqe[(size_t)bi * DEe + d] = s * (1.0f / Nn);
    }
}

__global__ __launch_bounds__(256) void dmean_col_kernel(
    const float* __restrict__ dist, const float* __restrict__ emb,
    float* __restrict__ dke)
{
    int bj = blockIdx.x;              // b*N + j
    int b = bj >> 9, j = bj & 511;
    int d = threadIdx.x & 63;
    int g = threadIdx.x >> 6;
    float acc = 0.f;
    for (int i = g; i < Nn; i += 4) {
        int id = (int)dist[((size_t)(b * Nn + i)) * Nn + j];
        id = min(max(id, 0), 200);
        acc += emb[id * DEe + d];
    }
    __shared__ float red[4][64];
    red[g][d] = acc;
    __syncthreads();
    if (g == 0) {
        float s = red[0][d] + red[1][d] + red[2][d] + red[3][d];
        dke[(size_t)bj * DEe + d] = s * (1.0f / Nn);
    }
}

// ---------------------------------------------------------------------------
// bf16 MFMA GEMM: C[M][Nc] = act( A[M][K] @ W[Nc][K]^T + bias + (R?) )
// ---------------------------------------------------------------------------
template<bool RELU, bool RES>
__global__ __launch_bounds__(256) void mgemm_kernel(
    const float* __restrict__ A, const float* __restrict__ W,
    const float* __restrict__ bias, const float* __restrict__ Rr,
    float* __restrict__ C, int M, int Nc, int K)
{
    __shared__ short As[64 * 64];
    __shared__ short Ws[64 * 64];
    int t = threadIdx.x;
    int lane = t & 63;
    int wid = t >> 6;                 // wave 0..3
    int wm = wid >> 1, wn = wid & 1;  // 2x2 wave grid
    int m0 = blockIdx.y * 64, n0 = blockIdx.x * 64;

    int lr = t >> 2;
    int c0 = (t & 3) * 16;
    int sw = (lr & 7) << 3;

    const float* Arow = A + (size_t)(m0 + lr) * K + c0;
    const float* Wrow = W + (size_t)(n0 + lr) * K + c0;

    f32x4 acc[2][2] = {};

    for (int kt = 0; kt < K; kt += 64) {
        {
            float4 v0 = *(const float4*)(Arow + kt);
            float4 v1 = *(const float4*)(Arow + kt + 4);
            float4 v2 = *(const float4*)(Arow + kt + 8);
            float4 v3 = *(const float4*)(Arow + kt + 12);
            bf16x8 p0 = {f2bf(v0.x), f2bf(v0.y), f2bf(v0.z), f2bf(v0.w),
                         f2bf(v1.x), f2bf(v1.y), f2bf(v1.z), f2bf(v1.w)};
            bf16x8 p1 = {f2bf(v2.x), f2bf(v2.y), f2bf(v2.z), f2bf(v2.w),
                         f2bf(v3.x), f2bf(v3.y), f2bf(v3.z), f2bf(v3.w)};
            *(bf16x8*)&As[lr * 64 + ((c0 + 0) ^ sw)] = p0;
            *(bf16x8*)&As[lr * 64 + ((c0 + 8) ^ sw)] = p1;
        }
        {
            float4 v0 = *(const float4*)(Wrow + kt);
            float4 v1 = *(const float4*)(Wrow + kt + 4);
            float4 v2 = *(const float4*)(Wrow + kt + 8);
            float4 v3 = *(const float4*)(Wrow + kt + 12);
            bf16x8 p0 = {f2bf(v0.x), f2bf(v0.y), f2bf(v0.z), f2bf(v0.w),
                         f2bf(v1.x), f2bf(v1.y), f2bf(v1.z), f2bf(v1.w)};
            bf16x8 p1 = {f2bf(v2.x), f2bf(v2.y), f2bf(v2.z), f2bf(v2.w),
                         f2bf(v3.x), f2bf(v3.y), f2bf(v3.z), f2bf(v3.w)};
            *(bf16x8*)&Ws[lr * 64 + ((c0 + 0) ^ sw)] = p0;
            *(bf16x8*)&Ws[lr * 64 + ((c0 + 8) ^ sw)] = p1;
        }
        __syncthreads();

        int kgrp = (lane >> 4) * 8;
#pragma unroll
        for (int kk = 0; kk < 64; kk += 32) {
            bf16x8 fa[2], fb[2];
            int ko = kk + kgrp;
#pragma unroll
            for (int mt = 0; mt < 2; ++mt) {
                int r = wm * 32 + mt * 16 + (lane & 15);
                fa[mt] = *(bf16x8*)&As[r * 64 + (ko ^ ((r & 7) << 3))];
            }
#pragma unroll
            for (int nt = 0; nt < 2; ++nt) {
                int r = wn * 32 + nt * 16 + (lane & 15);
                fb[nt] = *(bf16x8*)&Ws[r * 64 + (ko ^ ((r & 7) << 3))];
            }
#pragma unroll
            for (int mt = 0; mt < 2; ++mt)
#pragma unroll
                for (int nt = 0; nt < 2; ++nt)
                    acc[mt][nt] = __builtin_amdgcn_mfma_f32_16x16x32_bf16(
                        fa[mt], fb[nt], acc[mt][nt], 0, 0, 0);
        }
        __syncthreads();
    }

    int cr = (lane >> 4) * 4;
    int cc = lane & 15;
#pragma unroll
    for (int mt = 0; mt < 2; ++mt) {
#pragma unroll
        for (int nt = 0; nt < 2; ++nt) {
            int col = n0 + wn * 32 + nt * 16 + cc;
            float bv = bias[col];
#pragma unroll
            for (int r = 0; r < 4; ++r) {
                int row = m0 + wm * 32 + mt * 16 + cr + r;
                float o = acc[mt][nt][r] + bv;
                if (RES) o += Rr[(size_t)row * Nc + col];
                if (RELU) o = fmaxf(o, 0.f);
                C[(size_t)row * Nc + col] = o;
            }
        }
    }
}

// ---------------------------------------------------------------------------
// MFMA flash attention. One block per (b, h, 64-row q-tile). 4 waves; wave wq
// owns q rows [wq*16, wq*16+16). Swapped QK^T: S^T = mfma(K, Q) so q sits at
// lane&15; online softmax; PV as O^T = V^T @ P^T with V staged transposed.
// Layouts (lane = (g = lane>>4, c = lane&15)):
//   S^T frag s[kt]: score(q = wq*16+c, key = kt*16 + g*4 + reg)
//   O^T frag o[dt]: out(q = wq*16+c, d = dt*16 + g*4 + reg)
// ---------------------------------------------------------------------------
__global__ __launch_bounds__(256) void attn_mfma_kernel(
    const float* __restrict__ Qm, const float* __restrict__ Km,
    const float* __restrict__ Vm, const float* __restrict__ mask,
    float* __restrict__ AO)
{
    __shared__ short Qs[64 * 64];       // [q][d] bf16, XOR-swizzled
    __shared__ short Ks[64 * 64];       // [key][d] bf16, XOR-swizzled
    __shared__ short Vt[64 * 64];       // [d][key] bf16, XOR-swizzled
    __shared__ float Ms[64 * 65];       // [q][key] f32, stride 65
    __shared__ short Pl[4][16 * 72];    // per-wave P^T bounce: [q][key], stride 72

    int t = threadIdx.x;
    int lane = t & 63;
    int wq = t >> 6;
    int g = lane >> 4, cc = lane & 15;
    int q0 = blockIdx.x * 64;
    int h = blockIdx.y, b = blockIdx.z;

    int lr = t >> 2;            // staging row 0..63
    int c0 = (t & 3) * 16;      // staging col offset
    int sw = (lr & 7) << 3;
    int csw = (cc & 7) << 3;

    // ---- stage Q once (scaled by 1/sqrt(64)) ----
    {
        const float* src = Qm + ((size_t)(b * Nn + q0 + lr)) * Hh + h * HDd + c0;
        float4 v0 = *(const float4*)(src);
        float4 v1 = *(const float4*)(src + 4);
        float4 v2 = *(const float4*)(src + 8);
        float4 v3 = *(const float4*)(src + 12);
        const float sc = 0.125f;
        bf16x8 p0 = {f2bf(v0.x*sc), f2bf(v0.y*sc), f2bf(v0.z*sc), f2bf(v0.w*sc),
                     f2bf(v1.x*sc), f2bf(v1.y*sc), f2bf(v1.z*sc), f2bf(v1.w*sc)};
        bf16x8 p1 = {f2bf(v2.x*sc), f2bf(v2.y*sc), f2bf(v2.z*sc), f2bf(v2.w*sc),
                     f2bf(v3.x*sc), f2bf(v3.y*sc), f2bf(v3.z*sc), f2bf(v3.w*sc)};
        *(bf16x8*)&Qs[lr * 64 + ((c0 + 0) ^ sw)] = p0;
        *(bf16x8*)&Qs[lr * 64 + ((c0 + 8) ^ sw)] = p1;
    }

    // global bases for K/V/mask tiles
    const float* Krow = Km + ((size_t)(b * Nn + lr)) * Hh + h * HDd + c0;
    int vkey = t >> 4;              // 0..15
    int vd0 = (t & 15) * 4;
    const float* Vbase = Vm + ((size_t)(b * Nn)) * Hh + h * HDd + vd0;
    const float* Mrow = mask + ((size_t)(b * Nn + q0 + lr)) * Nn + c0;

    float4 kreg[4], vreg[4], mreg[4];
    auto issue = [&](int kc) {
        int k0 = kc * 64;
        const float* kp = Krow + (size_t)k0 * Hh;
        kreg[0] = *(const float4*)(kp);
        kreg[1] = *(const float4*)(kp + 4);
        kreg[2] = *(const float4*)(kp + 8);
        kreg[3] = *(const float4*)(kp + 12);
        const float* mp = Mrow + k0;
        mreg[0] = *(const float4*)(mp);
        mreg[1] = *(const float4*)(mp + 4);
        mreg[2] = *(const float4*)(mp + 8);
        mreg[3] = *(const float4*)(mp + 12);
#pragma unroll
        for (int p = 0; p < 4; ++p)
            vreg[p] = *(const float4*)(Vbase + (size_t)(k0 + vkey + p * 16) * Hh);
    };
    issue(0);
    __syncthreads();

    // hoist Q B-frags (wave-invariant across k-tiles)
    bf16x8 qf0 = *(bf16x8*)&Qs[(wq * 16 + cc) * 64 + ((0 + g * 8) ^ csw)];
    bf16x8 qf1 = *(bf16x8*)&Qs[(wq * 16 + cc) * 64 + ((32 + g * 8) ^ csw)];

    float m_run = -1e30f, l_run = 0.f;
    f32x4 o[4] = {};

    for (int kc = 0; kc < 8; ++kc) {
        // ---- write staged regs -> LDS ----
        {
            bf16x8 p0 = {f2bf(kreg[0].x), f2bf(kreg[0].y), f2bf(kreg[0].z), f2bf(kreg[0].w),
                         f2bf(kreg[1].x), f2bf(kreg[1].y), f2bf(kreg[1].z), f2bf(kreg[1].w)};
            bf16x8 p1 = {f2bf(kreg[2].x), f2bf(kreg[2].y), f2bf(kreg[2].z), f2bf(kreg[2].w),
                         f2bf(kreg[3].x), f2bf(kreg[3].y), f2bf(kreg[3].z), f2bf(kreg[3].w)};
            *(bf16x8*)&Ks[lr * 64 + ((c0 + 0) ^ sw)] = p0;
            *(bf16x8*)&Ks[lr * 64 + ((c0 + 8) ^ sw)] = p1;

            float* msr = &Ms[lr * 65 + c0];
            msr[0] = mreg[0].x;  msr[1] = mreg[0].y;  msr[2] = mreg[0].z;  msr[3] = mreg[0].w;
            msr[4] = mreg[1].x;  msr[5] = mreg[1].y;  msr[6] = mreg[1].z;  msr[7] = mreg[1].w;
            msr[8] = mreg[2].x;  msr[9] = mreg[2].y;  msr[10] = mreg[2].z; msr[11] = mreg[2].w;
            msr[12] = mreg[3].x; msr[13] = mreg[3].y; msr[14] = mreg[3].z; msr[15] = mreg[3].w;

#pragma unroll
            for (int p = 0; p < 4; ++p) {
                int key = vkey + p * 16;
                float vals[4] = {vreg[p].x, vreg[p].y, vreg[p].z, vreg[p].w};
#pragma unroll
                for (int jj = 0; jj < 4; ++jj) {
                    int j = (jj + (t >> 2)) & 3;     // rotate to spread banks
                    int d = vd0 + j;
                    Vt[d * 64 + (key ^ ((d & 7) << 3))] = f2bf(vals[j]);
                }
            }
        }
        __syncthreads();
        if (kc < 7) issue(kc + 1);

        // ---- QK^T (swapped): s[kt] over keys kt*16.. ----
        f32x4 s[4] = {};
#pragma unroll
        for (int kt = 0; kt < 4; ++kt) {
            bf16x8 a0 = *(bf16x8*)&Ks[(kt * 16 + cc) * 64 + ((0 + g * 8) ^ csw)];
            s[kt] = __builtin_amdgcn_mfma_f32_16x16x32_bf16(a0, qf0, s[kt], 0, 0, 0);
            bf16x8 a1 = *(bf16x8*)&Ks[(kt * 16 + cc) * 64 + ((32 + g * 8) ^ csw)];
            s[kt] = __builtin_amdgcn_mfma_f32_16x16x32_bf16(a1, qf1, s[kt], 0, 0, 0);
        }

        // ---- mask + online softmax ----
        float pv[4][4];
        float tmax = -1e30f;
#pragma unroll
        for (int kt = 0; kt < 4; ++kt) {
#pragma unroll
            for (int r = 0; r < 4; ++r) {
                float mv = Ms[(wq * 16 + cc) * 65 + kt * 16 + g * 4 + r];
                float svv = (mv == 0.f) ? -1e30f : s[kt][r];
                pv[kt][r] = svv;
                tmax = fmaxf(tmax, svv);
            }
        }
        tmax = fmaxf(tmax, __shfl_xor(tmax, 16));
        tmax = fmaxf(tmax, __shfl_xor(tmax, 32));
        float mnew = fmaxf(m_run, tmax);
        float rescale = __expf(m_run - mnew);   // both -1e30 -> 1 (harmless, l=0)
        float psum = 0.f;
#pragma unroll
        for (int kt = 0; kt < 4; ++kt) {
#pragma unroll
            for (int r = 0; r < 4; ++r) {
                float sv = pv[kt][r];
                float p = (sv == -1e30f) ? 0.f : __expf(sv - mnew);
                pv[kt][r] = p;
                psum += p;
            }
        }
        psum += __shfl_xor(psum, 16);
        psum += __shfl_xor(psum, 32);
        l_run = l_run * rescale + psum;
        m_run = mnew;
#pragma unroll
        for (int dt = 0; dt < 4; ++dt) {
            o[dt][0] *= rescale; o[dt][1] *= rescale;
            o[dt][2] *= rescale; o[dt][3] *= rescale;
        }

        // ---- P^T -> per-wave LDS bounce ----
#pragma unroll
        for (int kt = 0; kt < 4; ++kt) {
            bf16x4 pk = {f2bf(pv[kt][0]), f2bf(pv[kt][1]),
                         f2bf(pv[kt][2]), f2bf(pv[kt][3])};
            *(bf16x4*)&Pl[wq][cc * 72 + kt * 16 + g * 4] = pk;
        }
        bf16x8 pf0 = *(bf16x8*)&Pl[wq][cc * 72 + 0 + g * 8];
        bf16x8 pf1 = *(bf16x8*)&Pl[wq][cc * 72 + 32 + g * 8];

        // ---- PV: o[dt] += V^T @ P^T ----
#pragma unroll
        for (int dt = 0; dt < 4; ++dt) {
            bf16x8 vf0 = *(bf16x8*)&Vt[(dt * 16 + cc) * 64 + ((0 + g * 8) ^ csw)];
            o[dt] = __builtin_amdgcn_mfma_f32_16x16x32_bf16(vf0, pf0, o[dt], 0, 0, 0);
            bf16x8 vf1 = *(bf16x8*)&Vt[(dt * 16 + cc) * 64 + ((32 + g * 8) ^ csw)];
            o[dt] = __builtin_amdgcn_mfma_f32_16x16x32_bf16(vf1, pf1, o[dt], 0, 0, 0);
        }
        __syncthreads();
    }

    // ---- epilogue: normalize and store ----
    float invl = 1.f / l_run;
#pragma unroll
    for (int dt = 0; dt < 4; ++dt) {
        float4 w = {o[dt][0] * invl, o[dt][1] * invl,
                    o[dt][2] * invl, o[dt][3] * invl};
        *(float4*)&AO[((size_t)(b * Nn + q0 + wq * 16 + cc)) * Hh +
                      h * HDd + dt * 16 + g * 4] = w;
    }
}

// ---------------------------------------------------------------------------
// GRU elementwise:  u = (1-z)*n + z*msg
// ---------------------------------------------------------------------------
__global__ __launch_bounds__(256) void gru_kernel(
    const float* __restrict__ gx, const float* __restrict__ gh,
    const float* __restrict__ msg, float* __restrict__ u)
{
    int i = blockIdx.x * 256 + threadIdx.x;
    int row = i >> 9, col = i & 511;
    const float* gxr = gx + (size_t)row * (3 * Hh);
    const float* ghr = gh + (size_t)row * (3 * Hh);
    float xr = gxr[col], xz = gxr[col + 512], xn = gxr[col + 1024];
    float hr = ghr[col], hz = ghr[col + 512], hn = ghr[col + 1024];
    float r = 1.f / (1.f + __expf(-(xr + hr)));
    float z = 1.f / (1.f + __expf(-(xz + hz)));
    float n = tanhf(xn + r * hn);
    u[i] = (1.f - z) * n + z * msg[i];
}

// ---------------------------------------------------------------------------
// LayerNorm over rows of 512
// ---------------------------------------------------------------------------
__global__ __launch_bounds__(256) void ln_kernel(
    const float* __restrict__ Y, const float* __restrict__ g,
    const float* __restrict__ be, float* __restrict__ out)
{
    int row = blockIdx.x, t = threadIdx.x;
    const float* yr = Y + (size_t)row * Hh;
    float v0 = yr[t], v1 = yr[t + 256];
    float s = v0 + v1, s2 = v0 * v0 + v1 * v1;
#pragma unroll
    for (int o = 1; o < 64; o <<= 1) {
        s += __shfl_xor(s, o);
        s2 += __shfl_xor(s2, o);
    }
    __shared__ float rs[4], rs2[4];
    int w = t >> 6;
    if ((t & 63) == 0) { rs[w] = s; rs2[w] = s2; }
    __syncthreads();
    float ts = rs[0] + rs[1] + rs[2] + rs[3];
    float ts2 = rs2[0] + rs2[1] + rs2[2] + rs2[3];
    float mu = ts * (1.0f / Hh);
    float var = ts2 * (1.0f / Hh) - mu * mu;
    float rstd = rsqrtf(var + EPSs);
    out[(size_t)row * Hh + t] = (v0 - mu) * rstd * g[t] + be[t];
    out[(size_t)row * Hh + t + 256] = (v1 - mu) * rstd * g[t + 256] + be[t + 256];
}

// ---------------------------------------------------------------------------
extern "C" void kernel_launch(void* const* d_in, const int* in_sizes, int n_in,
                              void* d_out, int out_size, void* d_ws, size_t ws_size,
                              hipStream_t stream) {
    const float* messages = (const float*)d_in[0];
    const float* dist     = (const float*)d_in[1];
    const float* mask     = (const float*)d_in[2];
    const float* emb      = (const float*)d_in[3];
    const float* Wdq = (const float*)d_in[4];  const float* bdq = (const float*)d_in[5];
    const float* Wdk = (const float*)d_in[6];  const float* bdk = (const float*)d_in[7];
    const float* Wq  = (const float*)d_in[8];  const float* bq  = (const float*)d_in[9];
    const float* Wk  = (const float*)d_in[10]; const float* bk  = (const float*)d_in[11];
    const float* Wv  = (const float*)d_in[12]; const float* bv  = (const float*)d_in[13];
    const float* Wo  = (const float*)d_in[14]; const float* bo  = (const float*)d_in[15];
    const float* W_ih = (const float*)d_in[16]; const float* b_ih = (const float*)d_in[17];
    const float* W_hh = (const float*)d_in[18]; const float* b_hh = (const float*)d_in[19];
    const float* W1  = (const float*)d_in[20]; const float* b1  = (const float*)d_in[21];
    const float* W2  = (const float*)d_in[22]; const float* b2  = (const float*)d_in[23];
    const float* g2  = (const float*)d_in[24]; const float* beta2 = (const float*)d_in[25];

    const int M = Bz * Nn;  // 2048

    float* w = (float*)d_ws;
    float* dqe = w;                         // 131072
    float* dke = dqe + 131072;              // 131072
    float* XQ  = dke + 131072;              // 1048576
    float* XK  = XQ + 1048576;              // 1048576
    float* Qb  = XK + 1048576;              // 1048576
    float* Kb  = Qb + 1048576;              // 1048576
    float* Vb  = Kb + 1048576;              // 1048576
    float* gx  = Vb + 1048576;              // 3145728
    float* gh  = gx + 3145728;              // 3145728
    // reuse (stream-serial, producers strictly after last consumers):
    float* AO  = XQ;   // XQ dead after Q GEMM
    float* ao  = XK;   // XK dead after K GEMM
    float* ub  = Qb;   // Q dead after attention
    float* f1  = gx;   // gx+gh dead after GRU
    float* yb  = Kb;   // K dead after attention

    dim3 blk(256);

    dmean_row_kernel<<<M, blk, 0, stream>>>(dist, emb, dqe);
    dmean_col_kernel<<<M, blk, 0, stream>>>(dist, emb, dke);

    // XQ = messages + dqe @ Wdq^T + bdq ; XK = messages + dke @ Wdk^T + bdk
    mgemm_kernel<false, true><<<dim3(Hh / 64, M / 64), blk, 0, stream>>>(
        dqe, Wdq, bdq, messages, XQ, M, Hh, DEe);
    mgemm_kernel<false, true><<<dim3(Hh / 64, M / 64), blk, 0, stream>>>(
        dke, Wdk, bdk, messages, XK, M, Hh, DEe);

    // Q, K, V projections
    mgemm_kernel<false, false><<<dim3(Hh / 64, M / 64), blk, 0, stream>>>(
        XQ, Wq, bq, nullptr, Qb, M, Hh, Hh);
    mgemm_kernel<false, false><<<dim3(Hh / 64, M / 64), blk, 0, stream>>>(
        XK, Wk, bk, nullptr, Kb, M, Hh, Hh);
    mgemm_kernel<false, false><<<dim3(Hh / 64, M / 64), blk, 0, stream>>>(
        messages, Wv, bv, nullptr, Vb, M, Hh, Hh);

    // attention (MFMA flash)
    attn_mfma_kernel<<<dim3(Nn / 64, NHh, Bz), blk, 0, stream>>>(
        Qb, Kb, Vb, mask, AO);

    // output projection
    mgemm_kernel<false, false><<<dim3(Hh / 64, M / 64), blk, 0, stream>>>(
        AO, Wo, bo, nullptr, ao, M, Hh, Hh);

    // GRU gates
    mgemm_kernel<false, false><<<dim3(3 * Hh / 64, M / 64), blk, 0, stream>>>(
        ao, W_ih, b_ih, nullptr, gx, M, 3 * Hh, Hh);
    mgemm_kernel<false, false><<<dim3(3 * Hh / 64, M / 64), blk, 0, stream>>>(
        messages, W_hh, b_hh, nullptr, gh, M, 3 * Hh, Hh);
    gru_kernel<<<(M * Hh) / 256, blk, 0, stream>>>(gx, gh, messages, ub);

    // FFN
    mgemm_kernel<true, false><<<dim3(DFFf / 64, M / 64), blk, 0, stream>>>(
        ub, W1, b1, nullptr, f1, M, DFFf, Hh);
    mgemm_kernel<false, true><<<dim3(Hh / 64, M / 64), blk, 0, stream>>>(
        f1, W2, b2, ub, yb, M, Hh, DFFf);

    // LayerNorm -> out
    ln_kernel<<<M, blk, 0, stream>>>(yb, g2, beta2, (float*)d_out);
}

// Round 5
// 191.071 us; speedup vs baseline: 1.9125x; 1.5355x over previous
//
#include <hip/hip_runtime.h>
#include <hip/hip_bf16.h>
#include <math.h>

#define Bz 4
#define Nn 512
#define Hh 512
#define NHh 8
#define HDd 64
#define DEe 64
#define DFFf 2048
#define EPSs 1e-5f

typedef __attribute__((ext_vector_type(8))) short bf16x8;
typedef __attribute__((ext_vector_type(4))) short bf16x4;
typedef __attribute__((ext_vector_type(4))) float f32x4;

__device__ inline short f2bf(float x) {
    unsigned u = __builtin_bit_cast(unsigned, x);
    unsigned r = (u + 0x7FFFu + ((u >> 16) & 1u)) >> 16;
    return (short)r;
}
__device__ inline float b2f(unsigned short u) {
    unsigned v = ((unsigned)u) << 16;
    return __builtin_bit_cast(float, v);
}
__device__ inline void gld16(const void* g, void* l) {
    __builtin_amdgcn_global_load_lds(
        (const __attribute__((address_space(1))) void*)g,
        (__attribute__((address_space(3))) void*)l, 16, 0, 0);
}

// ---------------------------------------------------------------------------
// Segmented f32 -> bf16 conversion (weights + messages), one kernel.
// ---------------------------------------------------------------------------
struct CvtArgs {
    const float* src[11];
    unsigned short* dst[11];
    int n[11];
};
__global__ __launch_bounds__(256) void cvt_kernel(CvtArgs a) {
    for (int sg = 0; sg < 11; ++sg) {
        const float4* s = (const float4*)a.src[sg];
        ushort4* d = (ushort4*)a.dst[sg];
        int n4 = a.n[sg] >> 2;
        for (int i = blockIdx.x * blockDim.x + threadIdx.x; i < n4;
             i += gridDim.x * blockDim.x) {
            float4 v = s[i];
            ushort4 o = {(unsigned short)f2bf(v.x), (unsigned short)f2bf(v.y),
                         (unsigned short)f2bf(v.z), (unsigned short)f2bf(v.w)};
            d[i] = o;
        }
    }
}

// ---------------------------------------------------------------------------
// Transpose dist (B, N, N): distT[b][j][i] = dist[b][i][j]
// ---------------------------------------------------------------------------
__global__ __launch_bounds__(256) void transpose_kernel(
    const float* __restrict__ dist, float* __restrict__ distT)
{
    __shared__ float T[64][68];
    int b = blockIdx.z;
    int i0 = blockIdx.y * 64, j0 = blockIdx.x * 64;
    int t = threadIdx.x;
    int rr = t >> 4, c4 = (t & 15) * 4;
#pragma unroll
    for (int p = 0; p < 4; ++p) {
        int r = rr + p * 16;
        float4 v = *(const float4*)&dist[((size_t)(b * Nn + i0 + r)) * Nn + j0 + c4];
        *(float4*)&T[r][c4] = v;
    }
    __syncthreads();
#pragma unroll
    for (int p = 0; p < 4; ++p) {
        int jr = rr + p * 16;
        float4 v = {T[c4 + 0][jr], T[c4 + 1][jr], T[c4 + 2][jr], T[c4 + 3][jr]};
        *(float4*)&distT[((size_t)(b * Nn + j0 + jr)) * Nn + i0 + c4] = v;
    }
}

// ---------------------------------------------------------------------------
// Distance-embedding mean over rows of `dist` (use distT for column means).
// out[bi][d] = (1/N) sum_n emb[idx[bi][n]][d]  (bf16 out)
// ---------------------------------------------------------------------------
__global__ __launch_bounds__(256) void dmean_kernel(
    const float* __restrict__ dist, const float* __restrict__ emb,
    unsigned short* __restrict__ out)
{
    int bi = blockIdx.x;
    int t = threadIdx.x;
    int d = t & 63;
    int g = t >> 6;
    const float* drow = dist + (size_t)bi * Nn + g * 128;
    float acc = 0.f;
#pragma unroll 4
    for (int it = 0; it < 32; ++it) {
        float4 v = *(const float4*)(drow + it * 4);
        int i0 = min(max((int)v.x, 0), 200);
        int i1 = min(max((int)v.y, 0), 200);
        int i2 = min(max((int)v.z, 0), 200);
        int i3 = min(max((int)v.w, 0), 200);
        acc += emb[i0 * DEe + d];
        acc += emb[i1 * DEe + d];
        acc += emb[i2 * DEe + d];
        acc += emb[i3 * DEe + d];
    }
    __shared__ float red[4][64];
    red[g][d] = acc;
    __syncthreads();
    if (g == 0) {
        float s = red[0][d] + red[1][d] + red[2][d] + red[3][d];
        out[(size_t)bi * DEe + d] = (unsigned short)f2bf(s * (1.0f / Nn));
    }
}

// ---------------------------------------------------------------------------
// bf16 MFMA GEMM with global_load_lds staging (m97-style 2-barrier loop).
// C[M][Nc] = act( A[M][K] @ W[Nc][K]^T + bias + residual )
// BK=64. 4 waves in 2x2. LDS linear dest; source pre-swizzled so that
// LDS[r][unit u] holds A[row r][unit u ^ (r&7)] (16B units along K).
// RESM: 0 none, 1 f32 residual, 2 bf16 residual. OUTF: 1 = f32 out else bf16.
// ---------------------------------------------------------------------------
template<int BM, int BN, int RELU, int RESM, int OUTF>
__global__ __launch_bounds__(256) void mg_kernel(
    const unsigned short* __restrict__ A, const unsigned short* __restrict__ W,
    const float* __restrict__ bias, const void* __restrict__ Rr,
    void* __restrict__ C, int M, int Nc, int K)
{
    constexpr int WM = BM / 2, WN = BN / 2;
    constexpr int MT = WM / 16, NT = WN / 16;
    constexpr int IPA = BM / 32, IPB = BN / 32;   // 1KB chunks per wave
    __shared__ unsigned short As[BM * 64];
    __shared__ unsigned short Bs[BN * 64];
    int t = threadIdx.x, lane = t & 63, wid = t >> 6;
    int wm = wid >> 1, wn = wid & 1;
    int m0 = blockIdx.y * BM, n0 = blockIdx.x * BN;
    int lrow8 = lane >> 3;
    int lunit = (lane & 7) ^ lrow8;     // inverse-swizzled source unit

    f32x4 acc[MT][NT] = {};

    for (int kt = 0; kt < K; kt += 64) {
#pragma unroll
        for (int i = 0; i < IPA; ++i) {
            int c = wid * IPA + i;
            const unsigned short* g =
                A + (size_t)(m0 + c * 8 + lrow8) * K + kt + lunit * 8;
            gld16(g, &As[c * 512]);
        }
#pragma unroll
        for (int i = 0; i < IPB; ++i) {
            int c = wid * IPB + i;
            const unsigned short* g =
                W + (size_t)(n0 + c * 8 + lrow8) * K + kt + lunit * 8;
            gld16(g, &Bs[c * 512]);
        }
        __syncthreads();

#pragma unroll
        for (int kk = 0; kk < 2; ++kk) {
            bf16x8 fa[MT], fb[NT];
            int ub = kk * 4 + (lane >> 4);
#pragma unroll
            for (int mt = 0; mt < MT; ++mt) {
                int r = wm * WM + mt * 16 + (lane & 15);
                fa[mt] = *(const bf16x8*)&As[r * 64 + ((ub ^ (r & 7)) << 3)];
            }
#pragma unroll
            for (int nt = 0; nt < NT; ++nt) {
                int r = wn * WN + nt * 16 + (lane & 15);
                fb[nt] = *(const bf16x8*)&Bs[r * 64 + ((ub ^ (r & 7)) << 3)];
            }
#pragma unroll
            for (int mt = 0; mt < MT; ++mt)
#pragma unroll
                for (int nt = 0; nt < NT; ++nt)
                    acc[mt][nt] = __builtin_amdgcn_mfma_f32_16x16x32_bf16(
                        fa[mt], fb[nt], acc[mt][nt], 0, 0, 0);
        }
        __syncthreads();
    }

    int cr = (lane >> 4) * 4, ccl = lane & 15;
#pragma unroll
    for (int mt = 0; mt < MT; ++mt) {
#pragma unroll
        for (int nt = 0; nt < NT; ++nt) {
            int col = n0 + wn * WN + nt * 16 + ccl;
            float bv = bias[col];
#pragma unroll
            for (int r = 0; r < 4; ++r) {
                int row = m0 + wm * WM + mt * 16 + cr + r;
                float o = acc[mt][nt][r] + bv;
                if (RESM == 1)
                    o += ((const float*)Rr)[(size_t)row * Nc + col];
                if (RESM == 2)
                    o += b2f(((const unsigned short*)Rr)[(size_t)row * Nc + col]);
                if (RELU) o = fmaxf(o, 0.f);
                if (OUTF)
                    ((float*)C)[(size_t)row * Nc + col] = o;
                else
                    ((unsigned short*)C)[(size_t)row * Nc + col] =
                        (unsigned short)f2bf(o);
            }
        }
    }
}

// ---------------------------------------------------------------------------
// MFMA flash attention (bf16 Q/K/V/AO). One block per (b, h, 64 q-rows).
// Swapped QK^T; online softmax with scale folded into exp; O^T = V^T @ P^T.
// ---------------------------------------------------------------------------
__global__ __launch_bounds__(256) void attn_mfma_kernel(
    const unsigned short* __restrict__ Qm, const unsigned short* __restrict__ Km,
    const unsigned short* __restrict__ Vm, const float* __restrict__ mask,
    unsigned short* __restrict__ AO)
{
    __shared__ unsigned short Qs[64 * 64];
    __shared__ unsigned short Ks[64 * 64];
    __shared__ unsigned short Vt[64 * 64];
    __shared__ float Ms[64 * 65];
    __shared__ unsigned short Pl[4][16 * 72];

    int t = threadIdx.x;
    int lane = t & 63;
    int wq = t >> 6;
    int g = lane >> 4, cc = lane & 15;
    int q0 = blockIdx.x * 64;
    int h = blockIdx.y, b = blockIdx.z;

    int lr = t >> 2;
    int u0 = (t & 3) * 2;           // two 16B units (8 bf16 each) per thread
    int c0f = (t & 3) * 16;         // mask: 16 floats per thread

    // ---- stage Q once (unscaled; scale folded into softmax) ----
    {
        const unsigned short* src =
            Qm + ((size_t)(b * Nn + q0 + lr)) * Hh + h * HDd + u0 * 8;
        bf16x8 p0 = *(const bf16x8*)(src);
        bf16x8 p1 = *(const bf16x8*)(src + 8);
        *(bf16x8*)&Qs[lr * 64 + ((u0 ^ (lr & 7)) << 3)] = p0;
        *(bf16x8*)&Qs[lr * 64 + (((u0 + 1) ^ (lr & 7)) << 3)] = p1;
    }

    const unsigned short* Krow = Km + ((size_t)(b * Nn + lr)) * Hh + h * HDd + u0 * 8;
    int vkey = t >> 4;
    int vd0 = (t & 15) * 4;
    const unsigned short* Vbase = Vm + ((size_t)(b * Nn)) * Hh + h * HDd + vd0;
    const float* Mrow = mask + ((size_t)(b * Nn + q0 + lr)) * Nn + c0f;

    bf16x8 kr0, kr1;
    ushort4 vr[4];
    float4 mreg[4];
    auto issue = [&](int kc) {
        int k0 = kc * 64;
        const unsigned short* kp = Krow + (size_t)k0 * Hh;
        kr0 = *(const bf16x8*)(kp);
        kr1 = *(const bf16x8*)(kp + 8);
        const float* mp = Mrow + k0;
        mreg[0] = *(const float4*)(mp);
        mreg[1] = *(const float4*)(mp + 4);
        mreg[2] = *(const float4*)(mp + 8);
        mreg[3] = *(const float4*)(mp + 12);
#pragma unroll
        for (int p = 0; p < 4; ++p)
            vr[p] = *(const ushort4*)(Vbase + (size_t)(k0 + vkey + p * 16) * Hh);
    };
    issue(0);
    __syncthreads();

    bf16x8 qf0 = *(bf16x8*)&Qs[(wq * 16 + cc) * 64 + (((0 * 4 + g) ^ (cc & 7)) << 3)];
    bf16x8 qf1 = *(bf16x8*)&Qs[(wq * 16 + cc) * 64 + (((1 * 4 + g) ^ (cc & 7)) << 3)];

    const float scale = 0.125f;     // 1/sqrt(64)
    float m_run = -1e30f, l_run = 0.f;
    f32x4 o[4] = {};

    for (int kc = 0; kc < 8; ++kc) {
        // ---- write staged regs -> LDS ----
        {
            *(bf16x8*)&Ks[lr * 64 + ((u0 ^ (lr & 7)) << 3)] = kr0;
            *(bf16x8*)&Ks[lr * 64 + (((u0 + 1) ^ (lr & 7)) << 3)] = kr1;

            float* msr = &Ms[lr * 65 + c0f];
            msr[0] = mreg[0].x;  msr[1] = mreg[0].y;  msr[2] = mreg[0].z;  msr[3] = mreg[0].w;
            msr[4] = mreg[1].x;  msr[5] = mreg[1].y;  msr[6] = mreg[1].z;  msr[7] = mreg[1].w;
            msr[8] = mreg[2].x;  msr[9] = mreg[2].y;  msr[10] = mreg[2].z; msr[11] = mreg[2].w;
            msr[12] = mreg[3].x; msr[13] = mreg[3].y; msr[14] = mreg[3].z; msr[15] = mreg[3].w;

#pragma unroll
            for (int p = 0; p < 4; ++p) {
                int key = vkey + p * 16;
                unsigned short vals[4] = {vr[p].x, vr[p].y, vr[p].z, vr[p].w};
#pragma unroll
                for (int jj = 0; jj < 4; ++jj) {
                    int j = (jj + (t >> 2)) & 3;
                    int d = vd0 + j;
                    Vt[d * 64 + (key ^ ((d & 7) << 3))] = vals[j];
                }
            }
        }
        __syncthreads();
        if (kc < 7) issue(kc + 1);

        // ---- QK^T (swapped) ----
        f32x4 s[4] = {};
#pragma unroll
        for (int kt = 0; kt < 4; ++kt) {
            int rA = kt * 16 + cc;
            bf16x8 a0 = *(bf16x8*)&Ks[rA * 64 + (((0 * 4 + g) ^ (rA & 7)) << 3)];
            s[kt] = __builtin_amdgcn_mfma_f32_16x16x32_bf16(a0, qf0, s[kt], 0, 0, 0);
            bf16x8 a1 = *(bf16x8*)&Ks[rA * 64 + (((1 * 4 + g) ^ (rA & 7)) << 3)];
            s[kt] = __builtin_amdgcn_mfma_f32_16x16x32_bf16(a1, qf1, s[kt], 0, 0, 0);
        }

        // ---- mask + online softmax (raw-score max; scale in exp) ----
        float pv[4][4];
        float tmax = -1e30f;
#pragma unroll
        for (int kt = 0; kt < 4; ++kt) {
#pragma unroll
            for (int r = 0; r < 4; ++r) {
                float mv = Ms[(wq * 16 + cc) * 65 + kt * 16 + g * 4 + r];
                float svv = (mv == 0.f) ? -1e30f : s[kt][r];
                pv[kt][r] = svv;
                tmax = fmaxf(tmax, svv);
            }
        }
        tmax = fmaxf(tmax, __shfl_xor(tmax, 16));
        tmax = fmaxf(tmax, __shfl_xor(tmax, 32));
        float mnew = fmaxf(m_run, tmax);
        float rescale = __expf((m_run - mnew) * scale);
        float psum = 0.f;
#pragma unroll
        for (int kt = 0; kt < 4; ++kt) {
#pragma unroll
            for (int r = 0; r < 4; ++r) {
                float sv = pv[kt][r];
                float p = (sv == -1e30f) ? 0.f : __expf((sv - mnew) * scale);
                pv[kt][r] = p;
                psum += p;
            }
        }
        psum += __shfl_xor(psum, 16);
        psum += __shfl_xor(psum, 32);
        l_run = l_run * rescale + psum;
        m_run = mnew;
#pragma unroll
        for (int dt = 0; dt < 4; ++dt) {
            o[dt][0] *= rescale; o[dt][1] *= rescale;
            o[dt][2] *= rescale; o[dt][3] *= rescale;
        }

        // ---- P^T bounce through per-wave LDS ----
#pragma unroll
        for (int kt = 0; kt < 4; ++kt) {
            bf16x4 pk = {f2bf(pv[kt][0]), f2bf(pv[kt][1]),
                         f2bf(pv[kt][2]), f2bf(pv[kt][3])};
            *(bf16x4*)&Pl[wq][cc * 72 + kt * 16 + g * 4] = pk;
        }
        bf16x8 pf0 = *(bf16x8*)&Pl[wq][cc * 72 + 0 + g * 8];
        bf16x8 pf1 = *(bf16x8*)&Pl[wq][cc * 72 + 32 + g * 8];

        // ---- PV ----
#pragma unroll
        for (int dt = 0; dt < 4; ++dt) {
            int rV = dt * 16 + cc;
            bf16x8 vf0 = *(bf16x8*)&Vt[rV * 64 + (((0 * 4 + g) ^ (rV & 7)) << 3)];
            o[dt] = __builtin_amdgcn_mfma_f32_16x16x32_bf16(vf0, pf0, o[dt], 0, 0, 0);
            bf16x8 vf1 = *(bf16x8*)&Vt[rV * 64 + (((1 * 4 + g) ^ (rV & 7)) << 3)];
            o[dt] = __builtin_amdgcn_mfma_f32_16x16x32_bf16(vf1, pf1, o[dt], 0, 0, 0);
        }
        __syncthreads();
    }

    float invl = 1.f / l_run;
#pragma unroll
    for (int dt = 0; dt < 4; ++dt) {
        ushort4 w = {(unsigned short)f2bf(o[dt][0] * invl),
                     (unsigned short)f2bf(o[dt][1] * invl),
                     (unsigned short)f2bf(o[dt][2] * invl),
                     (unsigned short)f2bf(o[dt][3] * invl)};
        *(ushort4*)&AO[((size_t)(b * Nn + q0 + wq * 16 + cc)) * Hh +
                       h * HDd + dt * 16 + g * 4] = w;
    }
}

// ---------------------------------------------------------------------------
// GRU elementwise (bf16 gates, f32 messages, bf16 out), 4 elems/thread
// ---------------------------------------------------------------------------
__global__ __launch_bounds__(256) void gru_kernel(
    const unsigned short* __restrict__ gx, const unsigned short* __restrict__ gh,
    const float* __restrict__ msg, unsigned short* __restrict__ u)
{
    int i4 = blockIdx.x * 256 + threadIdx.x;
    int e = i4 * 4;
    int row = e >> 9, col = e & 511;
    const unsigned short* gxr = gx + (size_t)row * (3 * Hh);
    const unsigned short* ghr = gh + (size_t)row * (3 * Hh);
    ushort4 xr4 = *(const ushort4*)(gxr + col);
    ushort4 xz4 = *(const ushort4*)(gxr + col + 512);
    ushort4 xn4 = *(const ushort4*)(gxr + col + 1024);
    ushort4 hr4 = *(const ushort4*)(ghr + col);
    ushort4 hz4 = *(const ushort4*)(ghr + col + 512);
    ushort4 hn4 = *(const ushort4*)(ghr + col + 1024);
    float4 mg4 = *(const float4*)(msg + e);
    float mv[4] = {mg4.x, mg4.y, mg4.z, mg4.w};
    unsigned short xr[4] = {xr4.x, xr4.y, xr4.z, xr4.w};
    unsigned short xz[4] = {xz4.x, xz4.y, xz4.z, xz4.w};
    unsigned short xn[4] = {xn4.x, xn4.y, xn4.z, xn4.w};
    unsigned short hr[4] = {hr4.x, hr4.y, hr4.z, hr4.w};
    unsigned short hz[4] = {hz4.x, hz4.y, hz4.z, hz4.w};
    unsigned short hn[4] = {hn4.x, hn4.y, hn4.z, hn4.w};
    ushort4 out;
    unsigned short* op = (unsigned short*)&out;
#pragma unroll
    for (int j = 0; j < 4; ++j) {
        float r = 1.f / (1.f + __expf(-(b2f(xr[j]) + b2f(hr[j]))));
        float z = 1.f / (1.f + __expf(-(b2f(xz[j]) + b2f(hz[j]))));
        float n = tanhf(b2f(xn[j]) + r * b2f(hn[j]));
        op[j] = (unsigned short)f2bf((1.f - z) * n + z * mv[j]);
    }
    *(ushort4*)(u + e) = out;
}

// ---------------------------------------------------------------------------
// LayerNorm over rows of 512 (f32 in, f32 out)
// ---------------------------------------------------------------------------
__global__ __launch_bounds__(256) void ln_kernel(
    const float* __restrict__ Y, const float* __restrict__ g,
    const float* __restrict__ be, float* __restrict__ out)
{
    int row = blockIdx.x, t = threadIdx.x;
    const float* yr = Y + (size_t)row * Hh;
    float v0 = yr[t], v1 = yr[t + 256];
    float s = v0 + v1, s2 = v0 * v0 + v1 * v1;
#pragma unroll
    for (int o = 1; o < 64; o <<= 1) {
        s += __shfl_xor(s, o);
        s2 += __shfl_xor(s2, o);
    }
    __shared__ float rs[4], rs2[4];
    int w = t >> 6;
    if ((t & 63) == 0) { rs[w] = s; rs2[w] = s2; }
    __syncthreads();
    float ts = rs[0] + rs[1] + rs[2] + rs[3];
    float ts2 = rs2[0] + rs2[1] + rs2[2] + rs2[3];
    float mu = ts * (1.0f / Hh);
    float var = ts2 * (1.0f / Hh) - mu * mu;
    float rstd = rsqrtf(var + EPSs);
    out[(size_t)row * Hh + t] = (v0 - mu) * rstd * g[t] + be[t];
    out[(size_t)row * Hh + t + 256] = (v1 - mu) * rstd * g[t + 256] + be[t + 256];
}

// ---------------------------------------------------------------------------
extern "C" void kernel_launch(void* const* d_in, const int* in_sizes, int n_in,
                              void* d_out, int out_size, void* d_ws, size_t ws_size,
                              hipStream_t stream) {
    const float* messages = (const float*)d_in[0];
    const float* dist     = (const float*)d_in[1];
    const float* mask     = (const float*)d_in[2];
    const float* emb      = (const float*)d_in[3];
    const float* Wdq = (const float*)d_in[4];  const float* bdq = (const float*)d_in[5];
    const float* Wdk = (const float*)d_in[6];  const float* bdk = (const float*)d_in[7];
    const float* Wq  = (const float*)d_in[8];  const float* bq  = (const float*)d_in[9];
    const float* Wk  = (const float*)d_in[10]; const float* bk  = (const float*)d_in[11];
    const float* Wv  = (const float*)d_in[12]; const float* bv  = (const float*)d_in[13];
    const float* Wo  = (const float*)d_in[14]; const float* bo  = (const float*)d_in[15];
    const float* W_ih = (const float*)d_in[16]; const float* b_ih = (const float*)d_in[17];
    const float* W_hh = (const float*)d_in[18]; const float* b_hh = (const float*)d_in[19];
    const float* W1  = (const float*)d_in[20]; const float* b1  = (const float*)d_in[21];
    const float* W2  = (const float*)d_in[22]; const float* b2  = (const float*)d_in[23];
    const float* g2  = (const float*)d_in[24]; const float* beta2 = (const float*)d_in[25];

    const int M = Bz * Nn;  // 2048
    char* ws = (char*)d_ws;

    // bf16 weight / activation workspace layout (bytes)
    unsigned short* wdqb = (unsigned short*)(ws + 0);         // 512x64
    unsigned short* wdkb = (unsigned short*)(ws + 65536);
    unsigned short* wqb  = (unsigned short*)(ws + 131072);    // 512x512
    unsigned short* wkb  = (unsigned short*)(ws + 655360);
    unsigned short* wvb  = (unsigned short*)(ws + 1179648);
    unsigned short* wob  = (unsigned short*)(ws + 1703936);
    unsigned short* wihb = (unsigned short*)(ws + 2228224);   // 1536x512
    unsigned short* whhb = (unsigned short*)(ws + 3801088);
    unsigned short* w1b  = (unsigned short*)(ws + 5373952);   // 2048x512
    unsigned short* w2b  = (unsigned short*)(ws + 7471104);   // 512x2048
    unsigned short* msgs = (unsigned short*)(ws + 9568256);   // 2048x512
    unsigned short* dqe  = (unsigned short*)(ws + 11665408);  // 2048x64
    unsigned short* dke  = (unsigned short*)(ws + 11927552);
    unsigned short* XQ   = (unsigned short*)(ws + 12189696);  // 2048x512
    unsigned short* XK   = (unsigned short*)(ws + 14286848);
    unsigned short* Qb   = (unsigned short*)(ws + 16384000);
    unsigned short* Kb   = (unsigned short*)(ws + 18481152);
    unsigned short* Vb   = (unsigned short*)(ws + 20578304);
    unsigned short* gx   = (unsigned short*)(ws + 22675456);  // 2048x1536
    unsigned short* gh   = (unsigned short*)(ws + 28966912);
    float*          distT = (float*)(ws + 35258368);          // 4 MB (dead early)
    float*          yb    = (float*)(ws + 35258368);          // 8 MB (alive late)
    // overlays (stream-serial liveness)
    unsigned short* AO = XQ;     // XQ dead after Q GEMM
    unsigned short* ao = XK;     // XK dead after K GEMM
    unsigned short* ub = Qb;     // Qb dead after attention
    unsigned short* f1 = gx;     // gx/gh dead after GRU (needs 8.4MB of 12.6MB)

    dim3 blk(256);

    // 0) convert weights + messages to bf16
    CvtArgs ca;
    ca.src[0] = messages; ca.dst[0] = msgs; ca.n[0] = M * Hh;
    ca.src[1] = Wdq;  ca.dst[1] = wdqb; ca.n[1] = Hh * DEe;
    ca.src[2] = Wdk;  ca.dst[2] = wdkb; ca.n[2] = Hh * DEe;
    ca.src[3] = Wq;   ca.dst[3] = wqb;  ca.n[3] = Hh * Hh;
    ca.src[4] = Wk;   ca.dst[4] = wkb;  ca.n[4] = Hh * Hh;
    ca.src[5] = Wv;   ca.dst[5] = wvb;  ca.n[5] = Hh * Hh;
    ca.src[6] = Wo;   ca.dst[6] = wob;  ca.n[6] = Hh * Hh;
    ca.src[7] = W_ih; ca.dst[7] = wihb; ca.n[7] = 3 * Hh * Hh;
    ca.src[8] = W_hh; ca.dst[8] = whhb; ca.n[8] = 3 * Hh * Hh;
    ca.src[9] = W1;   ca.dst[9] = w1b;  ca.n[9] = DFFf * Hh;
    ca.src[10] = W2;  ca.dst[10] = w2b; ca.n[10] = Hh * DFFf;
    cvt_kernel<<<512, blk, 0, stream>>>(ca);

    // 1) dist transpose + distance-embedding means
    transpose_kernel<<<dim3(8, 8, Bz), blk, 0, stream>>>(dist, distT);
    dmean_kernel<<<M, blk, 0, stream>>>(dist, emb, dqe);
    dmean_kernel<<<M, blk, 0, stream>>>(distT, emb, dke);

    // 2) XQ/XK = messages + dmean @ Wd^T + b
    mg_kernel<128, 64, 0, 1, 0><<<dim3(8, 16), blk, 0, stream>>>(
        dqe, wdqb, bdq, messages, XQ, M, Hh, DEe);
    mg_kernel<128, 64, 0, 1, 0><<<dim3(8, 16), blk, 0, stream>>>(
        dke, wdkb, bdk, messages, XK, M, Hh, DEe);

    // 3) Q, K, V projections
    mg_kernel<128, 64, 0, 0, 0><<<dim3(8, 16), blk, 0, stream>>>(
        XQ, wqb, bq, nullptr, Qb, M, Hh, Hh);
    mg_kernel<128, 64, 0, 0, 0><<<dim3(8, 16), blk, 0, stream>>>(
        XK, wkb, bk, nullptr, Kb, M, Hh, Hh);
    mg_kernel<128, 64, 0, 0, 0><<<dim3(8, 16), blk, 0, stream>>>(
        msgs, wvb, bv, nullptr, Vb, M, Hh, Hh);

    // 4) attention
    attn_mfma_kernel<<<dim3(Nn / 64, NHh, Bz), blk, 0, stream>>>(
        Qb, Kb, Vb, mask, AO);

    // 5) output projection
    mg_kernel<128, 64, 0, 0, 0><<<dim3(8, 16), blk, 0, stream>>>(
        AO, wob, bo, nullptr, ao, M, Hh, Hh);

    // 6) GRU gates + elementwise
    mg_kernel<128, 128, 0, 0, 0><<<dim3(12, 16), blk, 0, stream>>>(
        ao, wihb, b_ih, nullptr, gx, M, 3 * Hh, Hh);
    mg_kernel<128, 128, 0, 0, 0><<<dim3(12, 16), blk, 0, stream>>>(
        msgs, whhb, b_hh, nullptr, gh, M, 3 * Hh, Hh);
    gru_kernel<<<(M * Hh) / 1024, blk, 0, stream>>>(gx, gh, messages, ub);

    // 7) FFN
    mg_kernel<128, 128, 1, 0, 0><<<dim3(16, 16), blk, 0, stream>>>(
        ub, w1b, b1, nullptr, f1, M, DFFf, Hh);
    mg_kernel<128, 64, 0, 2, 1><<<dim3(8, 16), blk, 0, stream>>>(
        f1, w2b, b2, ub, yb, M, Hh, DFFf);

    // 8) LayerNorm -> out
    ln_kernel<<<M, blk, 0, stream>>>(yb, g2, beta2, (float*)d_out);
}

// Round 6
// 159.830 us; speedup vs baseline: 2.2863x; 1.1955x over previous
//
#include <hip/hip_runtime.h>
#include <hip/hip_bf16.h>
#include <math.h>

#define Bz 4
#define Nn 512
#define Hh 512
#define NHh 8
#define HDd 64
#define DEe 64
#define DFFf 2048
#define EPSs 1e-5f
#define QS 1536      // fused QKV row stride
#define GS 3072      // fused gate row stride

typedef __attribute__((ext_vector_type(8))) short bf16x8;
typedef __attribute__((ext_vector_type(4))) short bf16x4;
typedef __attribute__((ext_vector_type(4))) float f32x4;

__device__ inline short f2bf(float x) {
    unsigned u = __builtin_bit_cast(unsigned, x);
    unsigned r = (u + 0x7FFFu + ((u >> 16) & 1u)) >> 16;
    return (short)r;
}
__device__ inline float b2f(unsigned short u) {
    unsigned v = ((unsigned)u) << 16;
    return __builtin_bit_cast(float, v);
}
__device__ inline void gld16(const void* g, void* l) {
    __builtin_amdgcn_global_load_lds(
        (const __attribute__((address_space(1))) void*)g,
        (__attribute__((address_space(3))) void*)l, 16, 0, 0);
}

// ---------------------------------------------------------------------------
// Segmented f32 -> bf16 conversion (weights + messages), one kernel.
// ---------------------------------------------------------------------------
struct CvtArgs {
    const float* src[11];
    unsigned short* dst[11];
    int n[11];
};
__global__ __launch_bounds__(256) void cvt_kernel(CvtArgs a) {
    for (int sg = 0; sg < 11; ++sg) {
        const float4* s = (const float4*)a.src[sg];
        ushort4* d = (ushort4*)a.dst[sg];
        int n4 = a.n[sg] >> 2;
        for (int i = blockIdx.x * blockDim.x + threadIdx.x; i < n4;
             i += gridDim.x * blockDim.x) {
            float4 v = s[i];
            ushort4 o = {(unsigned short)f2bf(v.x), (unsigned short)f2bf(v.y),
                         (unsigned short)f2bf(v.z), (unsigned short)f2bf(v.w)};
            d[i] = o;
        }
    }
}

// ---------------------------------------------------------------------------
// Transpose dist (B, N, N): distT[b][j][i] = dist[b][i][j]
// ---------------------------------------------------------------------------
__global__ __launch_bounds__(256) void transpose_kernel(
    const float* __restrict__ dist, float* __restrict__ distT)
{
    __shared__ float T[64][68];
    int b = blockIdx.z;
    int i0 = blockIdx.y * 64, j0 = blockIdx.x * 64;
    int t = threadIdx.x;
    int rr = t >> 4, c4 = (t & 15) * 4;
#pragma unroll
    for (int p = 0; p < 4; ++p) {
        int r = rr + p * 16;
        float4 v = *(const float4*)&dist[((size_t)(b * Nn + i0 + r)) * Nn + j0 + c4];
        *(float4*)&T[r][c4] = v;
    }
    __syncthreads();
#pragma unroll
    for (int p = 0; p < 4; ++p) {
        int jr = rr + p * 16;
        float4 v = {T[c4 + 0][jr], T[c4 + 1][jr], T[c4 + 2][jr], T[c4 + 3][jr]};
        *(float4*)&distT[((size_t)(b * Nn + j0 + jr)) * Nn + i0 + c4] = v;
    }
}

// ---------------------------------------------------------------------------
// Distance-embedding mean; blockIdx.y selects (dist -> dqe) / (distT -> dke)
// ---------------------------------------------------------------------------
__global__ __launch_bounds__(256) void dmean2_kernel(
    const float* __restrict__ dist, const float* __restrict__ distT,
    const float* __restrict__ emb,
    unsigned short* __restrict__ dqe, unsigned short* __restrict__ dke)
{
    int bi = blockIdx.x;
    const float* src = blockIdx.y ? distT : dist;
    unsigned short* out = blockIdx.y ? dke : dqe;
    int t = threadIdx.x;
    int d = t & 63;
    int g = t >> 6;
    const float* drow = src + (size_t)bi * Nn + g * 128;
    float acc = 0.f;
#pragma unroll 4
    for (int it = 0; it < 32; ++it) {
        float4 v = *(const float4*)(drow + it * 4);
        int i0 = min(max((int)v.x, 0), 200);
        int i1 = min(max((int)v.y, 0), 200);
        int i2 = min(max((int)v.z, 0), 200);
        int i3 = min(max((int)v.w, 0), 200);
        acc += emb[i0 * DEe + d];
        acc += emb[i1 * DEe + d];
        acc += emb[i2 * DEe + d];
        acc += emb[i3 * DEe + d];
    }
    __shared__ float red[4][64];
    red[g][d] = acc;
    __syncthreads();
    if (g == 0) {
        float s = red[0][d] + red[1][d] + red[2][d] + red[3][d];
        out[(size_t)bi * DEe + d] = (unsigned short)f2bf(s * (1.0f / Nn));
    }
}

// ---------------------------------------------------------------------------
// Fused bf16 MFMA GEMM, up to 3 N-segments (per-segment A/lda/bias/residual).
// C[M][Ntot] = act( A_seg[M][K] @ W[Ntot][K]^T + bias_seg + residual_seg )
// BK=64, 4 waves 2x2, global_load_lds staging (linear LDS dest, source
// pre-swizzled; ds_read applies matching XOR).
// RESM: 0 none, 1 f32 residual, 2 bf16 residual. OUTF: 1 f32 out, 0 bf16.
// ---------------------------------------------------------------------------
struct SegArgs {
    const unsigned short* A[3];
    int lda[3];
    const float* bias[3];
    const void* res[3];
    int rlda;
};

template<int BM, int BN, int RELU, int RESM, int OUTF>
__global__ __launch_bounds__(256) void mgf_kernel(
    SegArgs sa, const unsigned short* __restrict__ W,
    void* __restrict__ C, int K, int SW, int ldc)
{
    constexpr int WM = BM / 2, WN = BN / 2;
    constexpr int MT = WM / 16, NT = WN / 16;
    constexpr int IPA = BM / 32, IPB = BN / 32;
    __shared__ unsigned short As[BM * 64];
    __shared__ unsigned short Bs[BN * 64];
    int t = threadIdx.x, lane = t & 63, wid = t >> 6;
    int wm = wid >> 1, wn = wid & 1;
    int m0 = blockIdx.y * BM, n0 = blockIdx.x * BN;
    int seg = n0 / SW;
    int segbase = seg * SW;
    const unsigned short* A = sa.A[seg];
    int lda = sa.lda[seg];
    int lrow8 = lane >> 3;
    int lunit = (lane & 7) ^ lrow8;     // inverse-swizzled source unit

    f32x4 acc[MT][NT] = {};

    for (int kt = 0; kt < K; kt += 64) {
#pragma unroll
        for (int i = 0; i < IPA; ++i) {
            int c = wid * IPA + i;
            const unsigned short* g =
                A + (size_t)(m0 + c * 8 + lrow8) * lda + kt + lunit * 8;
            gld16(g, &As[c * 512]);
        }
#pragma unroll
        for (int i = 0; i < IPB; ++i) {
            int c = wid * IPB + i;
            const unsigned short* g =
                W + (size_t)(n0 + c * 8 + lrow8) * K + kt + lunit * 8;
            gld16(g, &Bs[c * 512]);
        }
        __syncthreads();

#pragma unroll
        for (int kk = 0; kk < 2; ++kk) {
            bf16x8 fa[MT], fb[NT];
            int ub = kk * 4 + (lane >> 4);
#pragma unroll
            for (int mt = 0; mt < MT; ++mt) {
                int r = wm * WM + mt * 16 + (lane & 15);
                fa[mt] = *(const bf16x8*)&As[r * 64 + ((ub ^ (r & 7)) << 3)];
            }
#pragma unroll
            for (int nt = 0; nt < NT; ++nt) {
                int r = wn * WN + nt * 16 + (lane & 15);
                fb[nt] = *(const bf16x8*)&Bs[r * 64 + ((ub ^ (r & 7)) << 3)];
            }
#pragma unroll
            for (int mt = 0; mt < MT; ++mt)
#pragma unroll
                for (int nt = 0; nt < NT; ++nt)
                    acc[mt][nt] = __builtin_amdgcn_mfma_f32_16x16x32_bf16(
                        fa[mt], fb[nt], acc[mt][nt], 0, 0, 0);
        }
        __syncthreads();
    }

    int cr = (lane >> 4) * 4, ccl = lane & 15;
#pragma unroll
    for (int mt = 0; mt < MT; ++mt) {
#pragma unroll
        for (int nt = 0; nt < NT; ++nt) {
            int col = n0 + wn * WN + nt * 16 + ccl;
            int lcol = col - segbase;
            float bv = sa.bias[seg][lcol];
#pragma unroll
            for (int r = 0; r < 4; ++r) {
                int row = m0 + wm * WM + mt * 16 + cr + r;
                float o = acc[mt][nt][r] + bv;
                if (RESM == 1)
                    o += ((const float*)sa.res[seg])[(size_t)row * sa.rlda + lcol];
                if (RESM == 2)
                    o += b2f(((const unsigned short*)sa.res[seg])
                                 [(size_t)row * sa.rlda + lcol]);
                if (RELU) o = fmaxf(o, 0.f);
                if (OUTF)
                    ((float*)C)[(size_t)row * ldc + col] = o;
                else
                    ((unsigned short*)C)[(size_t)row * ldc + col] =
                        (unsigned short)f2bf(o);
            }
        }
    }
}

// ---------------------------------------------------------------------------
// MFMA flash attention reading fused QKV [M, 1536] (Q +0, K +512, V +1024).
// One block per (b, h, 64 q-rows); swapped QK^T; online softmax; O^T=V^T@P^T.
// ---------------------------------------------------------------------------
__global__ __launch_bounds__(256) void attn_mfma_kernel(
    const unsigned short* __restrict__ QKV, const float* __restrict__ mask,
    unsigned short* __restrict__ AO)
{
    __shared__ unsigned short Qs[64 * 64];
    __shared__ unsigned short Ks[64 * 64];
    __shared__ unsigned short Vt[64 * 64];
    __shared__ float Ms[64 * 65];
    __shared__ unsigned short Pl[4][16 * 72];

    int t = threadIdx.x;
    int lane = t & 63;
    int wq = t >> 6;
    int g = lane >> 4, cc = lane & 15;
    int q0 = blockIdx.x * 64;
    int h = blockIdx.y, b = blockIdx.z;

    int lr = t >> 2;
    int u0 = (t & 3) * 2;
    int c0f = (t & 3) * 16;

    // ---- stage Q once ----
    {
        const unsigned short* src =
            QKV + ((size_t)(b * Nn + q0 + lr)) * QS + h * HDd + u0 * 8;
        bf16x8 p0 = *(const bf16x8*)(src);
        bf16x8 p1 = *(const bf16x8*)(src + 8);
        *(bf16x8*)&Qs[lr * 64 + ((u0 ^ (lr & 7)) << 3)] = p0;
        *(bf16x8*)&Qs[lr * 64 + (((u0 + 1) ^ (lr & 7)) << 3)] = p1;
    }

    const unsigned short* Krow =
        QKV + ((size_t)(b * Nn + lr)) * QS + 512 + h * HDd + u0 * 8;
    int vkey = t >> 4;
    int vd0 = (t & 15) * 4;
    const unsigned short* Vbase =
        QKV + ((size_t)(b * Nn)) * QS + 1024 + h * HDd + vd0;
    const float* Mrow = mask + ((size_t)(b * Nn + q0 + lr)) * Nn + c0f;

    bf16x8 kr0, kr1;
    ushort4 vr[4];
    float4 mreg[4];
    auto issue = [&](int kc) {
        int k0 = kc * 64;
        const unsigned short* kp = Krow + (size_t)k0 * QS;
        kr0 = *(const bf16x8*)(kp);
        kr1 = *(const bf16x8*)(kp + 8);
        const float* mp = Mrow + k0;
        mreg[0] = *(const float4*)(mp);
        mreg[1] = *(const float4*)(mp + 4);
        mreg[2] = *(const float4*)(mp + 8);
        mreg[3] = *(const float4*)(mp + 12);
#pragma unroll
        for (int p = 0; p < 4; ++p)
            vr[p] = *(const ushort4*)(Vbase + (size_t)(k0 + vkey + p * 16) * QS);
    };
    issue(0);
    __syncthreads();

    bf16x8 qf0 = *(bf16x8*)&Qs[(wq * 16 + cc) * 64 + (((0 * 4 + g) ^ (cc & 7)) << 3)];
    bf16x8 qf1 = *(bf16x8*)&Qs[(wq * 16 + cc) * 64 + (((1 * 4 + g) ^ (cc & 7)) << 3)];

    const float scale = 0.125f;
    float m_run = -1e30f, l_run = 0.f;
    f32x4 o[4] = {};

    for (int kc = 0; kc < 8; ++kc) {
        {
            *(bf16x8*)&Ks[lr * 64 + ((u0 ^ (lr & 7)) << 3)] = kr0;
            *(bf16x8*)&Ks[lr * 64 + (((u0 + 1) ^ (lr & 7)) << 3)] = kr1;

            float* msr = &Ms[lr * 65 + c0f];
            msr[0] = mreg[0].x;  msr[1] = mreg[0].y;  msr[2] = mreg[0].z;  msr[3] = mreg[0].w;
            msr[4] = mreg[1].x;  msr[5] = mreg[1].y;  msr[6] = mreg[1].z;  msr[7] = mreg[1].w;
            msr[8] = mreg[2].x;  msr[9] = mreg[2].y;  msr[10] = mreg[2].z; msr[11] = mreg[2].w;
            msr[12] = mreg[3].x; msr[13] = mreg[3].y; msr[14] = mreg[3].z; msr[15] = mreg[3].w;

#pragma unroll
            for (int p = 0; p < 4; ++p) {
                int key = vkey + p * 16;
                unsigned short vals[4] = {vr[p].x, vr[p].y, vr[p].z, vr[p].w};
#pragma unroll
                for (int jj = 0; jj < 4; ++jj) {
                    int j = (jj + (t >> 2)) & 3;
                    int d = vd0 + j;
                    Vt[d * 64 + (key ^ ((d & 7) << 3))] = vals[j];
                }
            }
        }
        __syncthreads();
        if (kc < 7) issue(kc + 1);

        // ---- QK^T (swapped) ----
        f32x4 s[4] = {};
#pragma unroll
        for (int kt = 0; kt < 4; ++kt) {
            int rA = kt * 16 + cc;
            bf16x8 a0 = *(bf16x8*)&Ks[rA * 64 + (((0 * 4 + g) ^ (rA & 7)) << 3)];
            s[kt] = __builtin_amdgcn_mfma_f32_16x16x32_bf16(a0, qf0, s[kt], 0, 0, 0);
            bf16x8 a1 = *(bf16x8*)&Ks[rA * 64 + (((1 * 4 + g) ^ (rA & 7)) << 3)];
            s[kt] = __builtin_amdgcn_mfma_f32_16x16x32_bf16(a1, qf1, s[kt], 0, 0, 0);
        }

        // ---- mask + online softmax ----
        float pv[4][4];
        float tmax = -1e30f;
#pragma unroll
        for (int kt = 0; kt < 4; ++kt) {
#pragma unroll
            for (int r = 0; r < 4; ++r) {
                float mv = Ms[(wq * 16 + cc) * 65 + kt * 16 + g * 4 + r];
                float svv = (mv == 0.f) ? -1e30f : s[kt][r];
                pv[kt][r] = svv;
                tmax = fmaxf(tmax, svv);
            }
        }
        tmax = fmaxf(tmax, __shfl_xor(tmax, 16));
        tmax = fmaxf(tmax, __shfl_xor(tmax, 32));
        float mnew = fmaxf(m_run, tmax);
        float rescale = __expf((m_run - mnew) * scale);
        float psum = 0.f;
#pragma unroll
        for (int kt = 0; kt < 4; ++kt) {
#pragma unroll
            for (int r = 0; r < 4; ++r) {
                float sv = pv[kt][r];
                float p = (sv == -1e30f) ? 0.f : __expf((sv - mnew) * scale);
                pv[kt][r] = p;
                psum += p;
            }
        }
        psum += __shfl_xor(psum, 16);
        psum += __shfl_xor(psum, 32);
        l_run = l_run * rescale + psum;
        m_run = mnew;
#pragma unroll
        for (int dt = 0; dt < 4; ++dt) {
            o[dt][0] *= rescale; o[dt][1] *= rescale;
            o[dt][2] *= rescale; o[dt][3] *= rescale;
        }

        // ---- P^T bounce through per-wave LDS ----
#pragma unroll
        for (int kt = 0; kt < 4; ++kt) {
            bf16x4 pk = {f2bf(pv[kt][0]), f2bf(pv[kt][1]),
                         f2bf(pv[kt][2]), f2bf(pv[kt][3])};
            *(bf16x4*)&Pl[wq][cc * 72 + kt * 16 + g * 4] = pk;
        }
        bf16x8 pf0 = *(bf16x8*)&Pl[wq][cc * 72 + 0 + g * 8];
        bf16x8 pf1 = *(bf16x8*)&Pl[wq][cc * 72 + 32 + g * 8];

        // ---- PV ----
#pragma unroll
        for (int dt = 0; dt < 4; ++dt) {
            int rV = dt * 16 + cc;
            bf16x8 vf0 = *(bf16x8*)&Vt[rV * 64 + (((0 * 4 + g) ^ (rV & 7)) << 3)];
            o[dt] = __builtin_amdgcn_mfma_f32_16x16x32_bf16(vf0, pf0, o[dt], 0, 0, 0);
            bf16x8 vf1 = *(bf16x8*)&Vt[rV * 64 + (((1 * 4 + g) ^ (rV & 7)) << 3)];
            o[dt] = __builtin_amdgcn_mfma_f32_16x16x32_bf16(vf1, pf1, o[dt], 0, 0, 0);
        }
        __syncthreads();
    }

    float invl = 1.f / l_run;
#pragma unroll
    for (int dt = 0; dt < 4; ++dt) {
        ushort4 w = {(unsigned short)f2bf(o[dt][0] * invl),
                     (unsigned short)f2bf(o[dt][1] * invl),
                     (unsigned short)f2bf(o[dt][2] * invl),
                     (unsigned short)f2bf(o[dt][3] * invl)};
        *(ushort4*)&AO[((size_t)(b * Nn + q0 + wq * 16 + cc)) * Hh +
                       h * HDd + dt * 16 + g * 4] = w;
    }
}

// ---------------------------------------------------------------------------
// GRU elementwise reading fused gate buffer G [M, 3072] (gx +0, gh +1536)
// ---------------------------------------------------------------------------
__global__ __launch_bounds__(256) void gru_kernel(
    const unsigned short* __restrict__ G,
    const float* __restrict__ msg, unsigned short* __restrict__ u)
{
    int i4 = blockIdx.x * 256 + threadIdx.x;
    int e = i4 * 4;
    int row = e >> 9, col = e & 511;
    const unsigned short* gxr = G + (size_t)row * GS;
    const unsigned short* ghr = gxr + 1536;
    ushort4 xr4 = *(const ushort4*)(gxr + col);
    ushort4 xz4 = *(const ushort4*)(gxr + col + 512);
    ushort4 xn4 = *(const ushort4*)(gxr + col + 1024);
    ushort4 hr4 = *(const ushort4*)(ghr + col);
    ushort4 hz4 = *(const ushort4*)(ghr + col + 512);
    ushort4 hn4 = *(const ushort4*)(ghr + col + 1024);
    float4 mg4 = *(const float4*)(msg + e);
    float mv[4] = {mg4.x, mg4.y, mg4.z, mg4.w};
    unsigned short xr[4] = {xr4.x, xr4.y, xr4.z, xr4.w};
    unsigned short xz[4] = {xz4.x, xz4.y, xz4.z, xz4.w};
    unsigned short xn[4] = {xn4.x, xn4.y, xn4.z, xn4.w};
    unsigned short hr[4] = {hr4.x, hr4.y, hr4.z, hr4.w};
    unsigned short hz[4] = {hz4.x, hz4.y, hz4.z, hz4.w};
    unsigned short hn[4] = {hn4.x, hn4.y, hn4.z, hn4.w};
    ushort4 out;
    unsigned short* op = (unsigned short*)&out;
#pragma unroll
    for (int j = 0; j < 4; ++j) {
        float r = 1.f / (1.f + __expf(-(b2f(xr[j]) + b2f(hr[j]))));
        float z = 1.f / (1.f + __expf(-(b2f(xz[j]) + b2f(hz[j]))));
        float n = tanhf(b2f(xn[j]) + r * b2f(hn[j]));
        op[j] = (unsigned short)f2bf((1.f - z) * n + z * mv[j]);
    }
    *(ushort4*)(u + e) = out;
}

// ---------------------------------------------------------------------------
// LayerNorm over rows of 512 (f32 in, f32 out)
// ---------------------------------------------------------------------------
__global__ __launch_bounds__(256) void ln_kernel(
    const float* __restrict__ Y, const float* __restrict__ g,
    const float* __restrict__ be, float* __restrict__ out)
{
    int row = blockIdx.x, t = threadIdx.x;
    const float* yr = Y + (size_t)row * Hh;
    float v0 = yr[t], v1 = yr[t + 256];
    float s = v0 + v1, s2 = v0 * v0 + v1 * v1;
#pragma unroll
    for (int o = 1; o < 64; o <<= 1) {
        s += __shfl_xor(s, o);
        s2 += __shfl_xor(s2, o);
    }
    __shared__ float rs[4], rs2[4];
    int w = t >> 6;
    if ((t & 63) == 0) { rs[w] = s; rs2[w] = s2; }
    __syncthreads();
    float ts = rs[0] + rs[1] + rs[2] + rs[3];
    float ts2 = rs2[0] + rs2[1] + rs2[2] + rs2[3];
    float mu = ts * (1.0f / Hh);
    float var = ts2 * (1.0f / Hh) - mu * mu;
    float rstd = rsqrtf(var + EPSs);
    out[(size_t)row * Hh + t] = (v0 - mu) * rstd * g[t] + be[t];
    out[(size_t)row * Hh + t + 256] = (v1 - mu) * rstd * g[t + 256] + be[t + 256];
}

// ---------------------------------------------------------------------------
extern "C" void kernel_launch(void* const* d_in, const int* in_sizes, int n_in,
                              void* d_out, int out_size, void* d_ws, size_t ws_size,
                              hipStream_t stream) {
    const float* messages = (const float*)d_in[0];
    const float* dist     = (const float*)d_in[1];
    const float* mask     = (const float*)d_in[2];
    const float* emb      = (const float*)d_in[3];
    const float* Wdq = (const float*)d_in[4];  const float* bdq = (const float*)d_in[5];
    const float* Wdk = (const float*)d_in[6];  const float* bdk = (const float*)d_in[7];
    const float* Wq  = (const float*)d_in[8];  const float* bq  = (const float*)d_in[9];
    const float* Wk  = (const float*)d_in[10]; const float* bk  = (const float*)d_in[11];
    const float* Wv  = (const float*)d_in[12]; const float* bv  = (const float*)d_in[13];
    const float* Wo  = (const float*)d_in[14]; const float* bo  = (const float*)d_in[15];
    const float* W_ih = (const float*)d_in[16]; const float* b_ih = (const float*)d_in[17];
    const float* W_hh = (const float*)d_in[18]; const float* b_hh = (const float*)d_in[19];
    const float* W1  = (const float*)d_in[20]; const float* b1  = (const float*)d_in[21];
    const float* W2  = (const float*)d_in[22]; const float* b2  = (const float*)d_in[23];
    const float* g2  = (const float*)d_in[24]; const float* beta2 = (const float*)d_in[25];

    const int M = Bz * Nn;  // 2048
    char* ws = (char*)d_ws;

    // workspace layout (bytes); contiguity required for fused W blocks
    unsigned short* wdqb = (unsigned short*)(ws + 0);         // [512,64]
    unsigned short* wdkb = (unsigned short*)(ws + 65536);     // (wdqb||wdkb)
    unsigned short* wqkv = (unsigned short*)(ws + 131072);    // [1536,512] wq|wk|wv
    unsigned short* wob  = (unsigned short*)(ws + 1703936);   // [512,512]
    unsigned short* wgate= (unsigned short*)(ws + 2228224);   // [3072,512] wih|whh
    unsigned short* w1b  = (unsigned short*)(ws + 5373952);   // [2048,512]
    unsigned short* w2b  = (unsigned short*)(ws + 7471104);   // [512,2048]
    unsigned short* msgs = (unsigned short*)(ws + 9568256);   // [2048,512]
    unsigned short* dqe  = (unsigned short*)(ws + 11665408);  // [2048,64]
    unsigned short* dke  = (unsigned short*)(ws + 11927552);
    unsigned short* XQXK = (unsigned short*)(ws + 12189696);  // [2048,1024]
    unsigned short* QKVb = (unsigned short*)(ws + 16384000);  // [2048,1536]
    unsigned short* AO   = (unsigned short*)(ws + 22675456);  // [2048,512]
    unsigned short* aob  = (unsigned short*)(ws + 24772608);  // [2048,512]
    unsigned short* G    = (unsigned short*)(ws + 26869760);  // [2048,3072]
    unsigned short* ub   = (unsigned short*)(ws + 39452672);  // [2048,512]
    unsigned short* f1   = (unsigned short*)(ws + 41549824);  // [2048,2048]
    float*          yb   = (float*)(ws + 49938432);           // [2048,512] f32
    float*          distT= (float*)(ws + 54132736);           // [4,512,512] f32

    dim3 blk(256);

    // 0) convert weights + messages to bf16
    CvtArgs ca;
    ca.src[0] = messages; ca.dst[0] = msgs; ca.n[0] = M * Hh;
    ca.src[1] = Wdq;  ca.dst[1] = wdqb;          ca.n[1] = Hh * DEe;
    ca.src[2] = Wdk;  ca.dst[2] = wdkb;          ca.n[2] = Hh * DEe;
    ca.src[3] = Wq;   ca.dst[3] = wqkv;          ca.n[3] = Hh * Hh;
    ca.src[4] = Wk;   ca.dst[4] = wqkv + 262144; ca.n[4] = Hh * Hh;
    ca.src[5] = Wv;   ca.dst[5] = wqkv + 524288; ca.n[5] = Hh * Hh;
    ca.src[6] = Wo;   ca.dst[6] = wob;           ca.n[6] = Hh * Hh;
    ca.src[7] = W_ih; ca.dst[7] = wgate;         ca.n[7] = 3 * Hh * Hh;
    ca.src[8] = W_hh; ca.dst[8] = wgate + 786432;ca.n[8] = 3 * Hh * Hh;
    ca.src[9] = W1;   ca.dst[9] = w1b;           ca.n[9] = DFFf * Hh;
    ca.src[10] = W2;  ca.dst[10] = w2b;          ca.n[10] = Hh * DFFf;
    cvt_kernel<<<512, blk, 0, stream>>>(ca);

    // 1) dist transpose + fused distance-embedding means
    transpose_kernel<<<dim3(8, 8, Bz), blk, 0, stream>>>(dist, distT);
    dmean2_kernel<<<dim3(M, 2), blk, 0, stream>>>(dist, distT, emb, dqe, dke);

    // 2) fused XQ|XK = messages + dmean @ Wd^T   (N=1024, K=64)
    {
        SegArgs sa = {};
        sa.A[0] = dqe; sa.A[1] = dke; sa.lda[0] = 64; sa.lda[1] = 64;
        sa.bias[0] = bdq; sa.bias[1] = bdk;
        sa.res[0] = messages; sa.res[1] = messages; sa.rlda = Hh;
        mgf_kernel<128, 64, 0, 1, 0><<<dim3(16, 16), blk, 0, stream>>>(
            sa, wdqb, XQXK, DEe, 512, 1024);
    }

    // 3) fused Q|K|V projections  (N=1536, K=512)
    {
        SegArgs sa = {};
        sa.A[0] = XQXK; sa.A[1] = XQXK + 512; sa.A[2] = msgs;
        sa.lda[0] = 1024; sa.lda[1] = 1024; sa.lda[2] = 512;
        sa.bias[0] = bq; sa.bias[1] = bk; sa.bias[2] = bv;
        mgf_kernel<128, 128, 0, 0, 0><<<dim3(12, 16), blk, 0, stream>>>(
            sa, wqkv, QKVb, Hh, 512, QS);
    }

    // 4) attention
    attn_mfma_kernel<<<dim3(Nn / 64, NHh, Bz), blk, 0, stream>>>(
        QKVb, mask, AO);

    // 5) output projection
    {
        SegArgs sa = {};
        sa.A[0] = AO; sa.lda[0] = 512; sa.bias[0] = bo;
        mgf_kernel<128, 64, 0, 0, 0><<<dim3(8, 16), blk, 0, stream>>>(
            sa, wob, aob, Hh, 512, 512);
    }

    // 6) fused GRU gates gx|gh  (N=3072, K=512), then elementwise
    {
        SegArgs sa = {};
        sa.A[0] = aob; sa.A[1] = msgs; sa.lda[0] = 512; sa.lda[1] = 512;
        sa.bias[0] = b_ih; sa.bias[1] = b_hh;
        mgf_kernel<128, 128, 0, 0, 0><<<dim3(24, 16), blk, 0, stream>>>(
            sa, wgate, G, Hh, 1536, GS);
    }
    gru_kernel<<<(M * Hh) / 1024, blk, 0, stream>>>(G, messages, ub);

    // 7) FFN
    {
        SegArgs sa = {};
        sa.A[0] = ub; sa.lda[0] = 512; sa.bias[0] = b1;
        mgf_kernel<128, 128, 1, 0, 0><<<dim3(16, 16), blk, 0, stream>>>(
            sa, w1b, f1, Hh, 2048, DFFf);
    }
    {
        SegArgs sa = {};
        sa.A[0] = f1; sa.lda[0] = 2048; sa.bias[0] = b2;
        sa.res[0] = ub; sa.rlda = 512;
        mgf_kernel<128, 64, 0, 2, 1><<<dim3(8, 16), blk, 0, stream>>>(
            sa, w2b, yb, DFFf, 512, 512);
    }

    // 8) LayerNorm -> out
    ln_kernel<<<M, blk, 0, stream>>>(yb, g2, beta2, (float*)d_out);
}

// Round 7
// 144.618 us; speedup vs baseline: 2.5268x; 1.1052x over previous
//
#include <hip/hip_runtime.h>
#include <hip/hip_bf16.h>
#include <math.h>

#define Bz 4
#define Nn 512
#define Hh 512
#define NHh 8
#define HDd 64
#define DEe 64
#define DFFf 2048
#define EPSs 1e-5f
#define QS 1536      // fused QKV row stride
#define GS 3072      // fused gate row stride

typedef __attribute__((ext_vector_type(8))) short bf16x8;
typedef __attribute__((ext_vector_type(4))) short bf16x4;
typedef __attribute__((ext_vector_type(4))) float f32x4;

__device__ inline short f2bf(float x) {
    unsigned u = __builtin_bit_cast(unsigned, x);
    unsigned r = (u + 0x7FFFu + ((u >> 16) & 1u)) >> 16;
    return (short)r;
}
__device__ inline float b2f(unsigned short u) {
    unsigned v = ((unsigned)u) << 16;
    return __builtin_bit_cast(float, v);
}
__device__ inline void gld16(const void* g, void* l) {
    __builtin_amdgcn_global_load_lds(
        (const __attribute__((address_space(1))) void*)g,
        (__attribute__((address_space(3))) void*)l, 16, 0, 0);
}

// ---------------------------------------------------------------------------
// Merged: segmented f32->bf16 conversion (blocks 0..511) + dist transpose
// (blocks 512..767).
// ---------------------------------------------------------------------------
struct CvtArgs {
    const float* src[11];
    unsigned short* dst[11];
    int n[11];
};
__global__ __launch_bounds__(256) void cvttr_kernel(
    CvtArgs a, const float* __restrict__ dist, float* __restrict__ distT)
{
    __shared__ float T[64][68];
    int t = threadIdx.x;
    if (blockIdx.x < 512) {
        for (int sg = 0; sg < 11; ++sg) {
            const float4* s = (const float4*)a.src[sg];
            ushort4* d = (ushort4*)a.dst[sg];
            int n4 = a.n[sg] >> 2;
            for (int i = blockIdx.x * 256 + t; i < n4; i += 512 * 256) {
                float4 v = s[i];
                ushort4 o = {(unsigned short)f2bf(v.x), (unsigned short)f2bf(v.y),
                             (unsigned short)f2bf(v.z), (unsigned short)f2bf(v.w)};
                d[i] = o;
            }
        }
    } else {
        int tid = blockIdx.x - 512;           // 0..255
        int b = tid >> 6;
        int i0 = ((tid >> 3) & 7) * 64, j0 = (tid & 7) * 64;
        int rr = t >> 4, c4 = (t & 15) * 4;
#pragma unroll
        for (int p = 0; p < 4; ++p) {
            int r = rr + p * 16;
            float4 v = *(const float4*)&dist[((size_t)(b * Nn + i0 + r)) * Nn + j0 + c4];
            *(float4*)&T[r][c4] = v;
        }
        __syncthreads();
#pragma unroll
        for (int p = 0; p < 4; ++p) {
            int jr = rr + p * 16;
            float4 v = {T[c4 + 0][jr], T[c4 + 1][jr], T[c4 + 2][jr], T[c4 + 3][jr]};
            *(float4*)&distT[((size_t)(b * Nn + j0 + jr)) * Nn + i0 + c4] = v;
        }
    }
}

// ---------------------------------------------------------------------------
// Distance-embedding mean; blockIdx.y selects (dist -> dqe) / (distT -> dke)
// ---------------------------------------------------------------------------
__global__ __launch_bounds__(256) void dmean2_kernel(
    const float* __restrict__ dist, const float* __restrict__ distT,
    const float* __restrict__ emb,
    unsigned short* __restrict__ dqe, unsigned short* __restrict__ dke)
{
    int bi = blockIdx.x;
    const float* src = blockIdx.y ? distT : dist;
    unsigned short* out = blockIdx.y ? dke : dqe;
    int t = threadIdx.x;
    int d = t & 63;
    int g = t >> 6;
    const float* drow = src + (size_t)bi * Nn + g * 128;
    float acc = 0.f;
#pragma unroll 4
    for (int it = 0; it < 32; ++it) {
        float4 v = *(const float4*)(drow + it * 4);
        int i0 = min(max((int)v.x, 0), 200);
        int i1 = min(max((int)v.y, 0), 200);
        int i2 = min(max((int)v.z, 0), 200);
        int i3 = min(max((int)v.w, 0), 200);
        acc += emb[i0 * DEe + d];
        acc += emb[i1 * DEe + d];
        acc += emb[i2 * DEe + d];
        acc += emb[i3 * DEe + d];
    }
    __shared__ float red[4][64];
    red[g][d] = acc;
    __syncthreads();
    if (g == 0) {
        float s = red[0][d] + red[1][d] + red[2][d] + red[3][d];
        out[(size_t)bi * DEe + d] = (unsigned short)f2bf(s * (1.0f / Nn));
    }
}

// ---------------------------------------------------------------------------
// Fused bf16 MFMA GEMM, up to 3 N-segments, LDS double-buffered 2-phase:
// stage(next) -> compute(cur) -> barrier (drains). One barrier per K-step;
// next tile's global_load_lds fly during MFMA.
// RESM: 0 none, 1 f32 residual, 2 bf16 residual. OUTF: 1 f32 out, 0 bf16.
// ---------------------------------------------------------------------------
struct SegArgs {
    const unsigned short* A[3];
    int lda[3];
    const float* bias[3];
    const void* res[3];
    int rlda;
};

template<int BM, int BN, int RELU, int RESM, int OUTF>
__global__ __launch_bounds__(256) void mgf_kernel(
    SegArgs sa, const unsigned short* __restrict__ W,
    void* __restrict__ C, int K, int SW, int ldc)
{
    constexpr int WM = BM / 2, WN = BN / 2;
    constexpr int MT = WM / 16, NT = WN / 16;
    constexpr int IPA = BM / 32, IPB = BN / 32;
    __shared__ unsigned short As[2][BM * 64];
    __shared__ unsigned short Bs[2][BN * 64];
    int t = threadIdx.x, lane = t & 63, wid = t >> 6;
    int wm = wid >> 1, wn = wid & 1;
    int m0 = blockIdx.y * BM, n0 = blockIdx.x * BN;
    int seg = n0 / SW;
    int segbase = seg * SW;
    const unsigned short* A = sa.A[seg];
    int lda = sa.lda[seg];
    int lrow8 = lane >> 3;
    int lunit = (lane & 7) ^ lrow8;     // inverse-swizzled source unit

    f32x4 acc[MT][NT] = {};

    auto stage = [&](int buf, int kt) {
#pragma unroll
        for (int i = 0; i < IPA; ++i) {
            int c = wid * IPA + i;
            gld16(A + (size_t)(m0 + c * 8 + lrow8) * lda + kt + lunit * 8,
                  &As[buf][c * 512]);
        }
#pragma unroll
        for (int i = 0; i < IPB; ++i) {
            int c = wid * IPB + i;
            gld16(W + (size_t)(n0 + c * 8 + lrow8) * K + kt + lunit * 8,
                  &Bs[buf][c * 512]);
        }
    };

    stage(0, 0);
    __syncthreads();
    int cur = 0;
    for (int kt = 0; kt < K; kt += 64) {
        if (kt + 64 < K) stage(cur ^ 1, kt + 64);
#pragma unroll
        for (int kk = 0; kk < 2; ++kk) {
            bf16x8 fa[MT], fb[NT];
            int ub = kk * 4 + (lane >> 4);
#pragma unroll
            for (int mt = 0; mt < MT; ++mt) {
                int r = wm * WM + mt * 16 + (lane & 15);
                fa[mt] = *(const bf16x8*)&As[cur][r * 64 + ((ub ^ (r & 7)) << 3)];
            }
#pragma unroll
            for (int nt = 0; nt < NT; ++nt) {
                int r = wn * WN + nt * 16 + (lane & 15);
                fb[nt] = *(const bf16x8*)&Bs[cur][r * 64 + ((ub ^ (r & 7)) << 3)];
            }
#pragma unroll
            for (int mt = 0; mt < MT; ++mt)
#pragma unroll
                for (int nt = 0; nt < NT; ++nt)
                    acc[mt][nt] = __builtin_amdgcn_mfma_f32_16x16x32_bf16(
                        fa[mt], fb[nt], acc[mt][nt], 0, 0, 0);
        }
        __syncthreads();    // drains this iter's gld16 (vmcnt 0) + joins waves
        cur ^= 1;
    }

    int cr = (lane >> 4) * 4, ccl = lane & 15;
#pragma unroll
    for (int mt = 0; mt < MT; ++mt) {
#pragma unroll
        for (int nt = 0; nt < NT; ++nt) {
            int col = n0 + wn * WN + nt * 16 + ccl;
            int lcol = col - segbase;
            float bv = sa.bias[seg][lcol];
#pragma unroll
            for (int r = 0; r < 4; ++r) {
                int row = m0 + wm * WM + mt * 16 + cr + r;
                float o = acc[mt][nt][r] + bv;
                if (RESM == 1)
                    o += ((const float*)sa.res[seg])[(size_t)row * sa.rlda + lcol];
                if (RESM == 2)
                    o += b2f(((const unsigned short*)sa.res[seg])
                                 [(size_t)row * sa.rlda + lcol]);
                if (RELU) o = fmaxf(o, 0.f);
                if (OUTF)
                    ((float*)C)[(size_t)row * ldc + col] = o;
                else
                    ((unsigned short*)C)[(size_t)row * ldc + col] =
                        (unsigned short)f2bf(o);
            }
        }
    }
}

// ---------------------------------------------------------------------------
// MFMA flash attention reading fused QKV [M, 1536] (Q +0, K +512, V +1024).
// One block per (b, h, 64 q-rows); swapped QK^T; online softmax; O^T=V^T@P^T.
// ---------------------------------------------------------------------------
__global__ __launch_bounds__(256) void attn_mfma_kernel(
    const unsigned short* __restrict__ QKV, const float* __restrict__ mask,
    unsigned short* __restrict__ AO)
{
    __shared__ unsigned short Qs[64 * 64];
    __shared__ unsigned short Ks[64 * 64];
    __shared__ unsigned short Vt[64 * 64];
    __shared__ float Ms[64 * 65];
    __shared__ unsigned short Pl[4][16 * 72];

    int t = threadIdx.x;
    int lane = t & 63;
    int wq = t >> 6;
    int g = lane >> 4, cc = lane & 15;
    int q0 = blockIdx.x * 64;
    int h = blockIdx.y, b = blockIdx.z;

    int lr = t >> 2;
    int u0 = (t & 3) * 2;
    int c0f = (t & 3) * 16;

    // ---- stage Q once ----
    {
        const unsigned short* src =
            QKV + ((size_t)(b * Nn + q0 + lr)) * QS + h * HDd + u0 * 8;
        bf16x8 p0 = *(const bf16x8*)(src);
        bf16x8 p1 = *(const bf16x8*)(src + 8);
        *(bf16x8*)&Qs[lr * 64 + ((u0 ^ (lr & 7)) << 3)] = p0;
        *(bf16x8*)&Qs[lr * 64 + (((u0 + 1) ^ (lr & 7)) << 3)] = p1;
    }

    const unsigned short* Krow =
        QKV + ((size_t)(b * Nn + lr)) * QS + 512 + h * HDd + u0 * 8;
    int vkey = t >> 4;
    int vd0 = (t & 15) * 4;
    const unsigned short* Vbase =
        QKV + ((size_t)(b * Nn)) * QS + 1024 + h * HDd + vd0;
    const float* Mrow = mask + ((size_t)(b * Nn + q0 + lr)) * Nn + c0f;

    bf16x8 kr0, kr1;
    ushort4 vr[4];
    float4 mreg[4];
    auto issue = [&](int kc) {
        int k0 = kc * 64;
        const unsigned short* kp = Krow + (size_t)k0 * QS;
        kr0 = *(const bf16x8*)(kp);
        kr1 = *(const bf16x8*)(kp + 8);
        const float* mp = Mrow + k0;
        mreg[0] = *(const float4*)(mp);
        mreg[1] = *(const float4*)(mp + 4);
        mreg[2] = *(const float4*)(mp + 8);
        mreg[3] = *(const float4*)(mp + 12);
#pragma unroll
        for (int p = 0; p < 4; ++p)
            vr[p] = *(const ushort4*)(Vbase + (size_t)(k0 + vkey + p * 16) * QS);
    };
    issue(0);
    __syncthreads();

    bf16x8 qf0 = *(bf16x8*)&Qs[(wq * 16 + cc) * 64 + (((0 * 4 + g) ^ (cc & 7)) << 3)];
    bf16x8 qf1 = *(bf16x8*)&Qs[(wq * 16 + cc) * 64 + (((1 * 4 + g) ^ (cc & 7)) << 3)];

    const float scale = 0.125f;
    float m_run = -1e30f, l_run = 0.f;
    f32x4 o[4] = {};

    for (int kc = 0; kc < 8; ++kc) {
        {
            *(bf16x8*)&Ks[lr * 64 + ((u0 ^ (lr & 7)) << 3)] = kr0;
            *(bf16x8*)&Ks[lr * 64 + (((u0 + 1) ^ (lr & 7)) << 3)] = kr1;

            float* msr = &Ms[lr * 65 + c0f];
            msr[0] = mreg[0].x;  msr[1] = mreg[0].y;  msr[2] = mreg[0].z;  msr[3] = mreg[0].w;
            msr[4] = mreg[1].x;  msr[5] = mreg[1].y;  msr[6] = mreg[1].z;  msr[7] = mreg[1].w;
            msr[8] = mreg[2].x;  msr[9] = mreg[2].y;  msr[10] = mreg[2].z; msr[11] = mreg[2].w;
            msr[12] = mreg[3].x; msr[13] = mreg[3].y; msr[14] = mreg[3].z; msr[15] = mreg[3].w;

#pragma unroll
            for (int p = 0; p < 4; ++p) {
                int key = vkey + p * 16;
                unsigned short vals[4] = {vr[p].x, vr[p].y, vr[p].z, vr[p].w};
#pragma unroll
                for (int jj = 0; jj < 4; ++jj) {
                    int j = (jj + (t >> 2)) & 3;
                    int d = vd0 + j;
                    Vt[d * 64 + (key ^ ((d & 7) << 3))] = vals[j];
                }
            }
        }
        __syncthreads();
        if (kc < 7) issue(kc + 1);

        // ---- QK^T (swapped) ----
        f32x4 s[4] = {};
#pragma unroll
        for (int kt = 0; kt < 4; ++kt) {
            int rA = kt * 16 + cc;
            bf16x8 a0 = *(bf16x8*)&Ks[rA * 64 + (((0 * 4 + g) ^ (rA & 7)) << 3)];
            s[kt] = __builtin_amdgcn_mfma_f32_16x16x32_bf16(a0, qf0, s[kt], 0, 0, 0);
            bf16x8 a1 = *(bf16x8*)&Ks[rA * 64 + (((1 * 4 + g) ^ (rA & 7)) << 3)];
            s[kt] = __builtin_amdgcn_mfma_f32_16x16x32_bf16(a1, qf1, s[kt], 0, 0, 0);
        }

        // ---- mask + online softmax ----
        float pv[4][4];
        float tmax = -1e30f;
#pragma unroll
        for (int kt = 0; kt < 4; ++kt) {
#pragma unroll
            for (int r = 0; r < 4; ++r) {
                float mv = Ms[(wq * 16 + cc) * 65 + kt * 16 + g * 4 + r];
                float svv = (mv == 0.f) ? -1e30f : s[kt][r];
                pv[kt][r] = svv;
                tmax = fmaxf(tmax, svv);
            }
        }
        tmax = fmaxf(tmax, __shfl_xor(tmax, 16));
        tmax = fmaxf(tmax, __shfl_xor(tmax, 32));
        float mnew = fmaxf(m_run, tmax);
        float rescale = __expf((m_run - mnew) * scale);
        float psum = 0.f;
#pragma unroll
        for (int kt = 0; kt < 4; ++kt) {
#pragma unroll
            for (int r = 0; r < 4; ++r) {
                float sv = pv[kt][r];
                float p = (sv == -1e30f) ? 0.f : __expf((sv - mnew) * scale);
                pv[kt][r] = p;
                psum += p;
            }
        }
        psum += __shfl_xor(psum, 16);
        psum += __shfl_xor(psum, 32);
        l_run = l_run * rescale + psum;
        m_run = mnew;
#pragma unroll
        for (int dt = 0; dt < 4; ++dt) {
            o[dt][0] *= rescale; o[dt][1] *= rescale;
            o[dt][2] *= rescale; o[dt][3] *= rescale;
        }

        // ---- P^T bounce through per-wave LDS ----
#pragma unroll
        for (int kt = 0; kt < 4; ++kt) {
            bf16x4 pk = {f2bf(pv[kt][0]), f2bf(pv[kt][1]),
                         f2bf(pv[kt][2]), f2bf(pv[kt][3])};
            *(bf16x4*)&Pl[wq][cc * 72 + kt * 16 + g * 4] = pk;
        }
        bf16x8 pf0 = *(bf16x8*)&Pl[wq][cc * 72 + 0 + g * 8];
        bf16x8 pf1 = *(bf16x8*)&Pl[wq][cc * 72 + 32 + g * 8];

        // ---- PV ----
#pragma unroll
        for (int dt = 0; dt < 4; ++dt) {
            int rV = dt * 16 + cc;
            bf16x8 vf0 = *(bf16x8*)&Vt[rV * 64 + (((0 * 4 + g) ^ (rV & 7)) << 3)];
            o[dt] = __builtin_amdgcn_mfma_f32_16x16x32_bf16(vf0, pf0, o[dt], 0, 0, 0);
            bf16x8 vf1 = *(bf16x8*)&Vt[rV * 64 + (((1 * 4 + g) ^ (rV & 7)) << 3)];
            o[dt] = __builtin_amdgcn_mfma_f32_16x16x32_bf16(vf1, pf1, o[dt], 0, 0, 0);
        }
        __syncthreads();
    }

    float invl = 1.f / l_run;
#pragma unroll
    for (int dt = 0; dt < 4; ++dt) {
        ushort4 w = {(unsigned short)f2bf(o[dt][0] * invl),
                     (unsigned short)f2bf(o[dt][1] * invl),
                     (unsigned short)f2bf(o[dt][2] * invl),
                     (unsigned short)f2bf(o[dt][3] * invl)};
        *(ushort4*)&AO[((size_t)(b * Nn + q0 + wq * 16 + cc)) * Hh +
                       h * HDd + dt * 16 + g * 4] = w;
    }
}

// ---------------------------------------------------------------------------
// GRU elementwise reading fused gate buffer G [M, 3072] (gx +0, gh +1536)
// ---------------------------------------------------------------------------
__global__ __launch_bounds__(256) void gru_kernel(
    const unsigned short* __restrict__ G,
    const float* __restrict__ msg, unsigned short* __restrict__ u)
{
    int i4 = blockIdx.x * 256 + threadIdx.x;
    int e = i4 * 4;
    int row = e >> 9, col = e & 511;
    const unsigned short* gxr = G + (size_t)row * GS;
    const unsigned short* ghr = gxr + 1536;
    ushort4 xr4 = *(const ushort4*)(gxr + col);
    ushort4 xz4 = *(const ushort4*)(gxr + col + 512);
    ushort4 xn4 = *(const ushort4*)(gxr + col + 1024);
    ushort4 hr4 = *(const ushort4*)(ghr + col);
    ushort4 hz4 = *(const ushort4*)(ghr + col + 512);
    ushort4 hn4 = *(const ushort4*)(ghr + col + 1024);
    float4 mg4 = *(const float4*)(msg + e);
    float mv[4] = {mg4.x, mg4.y, mg4.z, mg4.w};
    unsigned short xr[4] = {xr4.x, xr4.y, xr4.z, xr4.w};
    unsigned short xz[4] = {xz4.x, xz4.y, xz4.z, xz4.w};
    unsigned short xn[4] = {xn4.x, xn4.y, xn4.z, xn4.w};
    unsigned short hr[4] = {hr4.x, hr4.y, hr4.z, hr4.w};
    unsigned short hz[4] = {hz4.x, hz4.y, hz4.z, hz4.w};
    unsigned short hn[4] = {hn4.x, hn4.y, hn4.z, hn4.w};
    ushort4 out;
    unsigned short* op = (unsigned short*)&out;
#pragma unroll
    for (int j = 0; j < 4; ++j) {
        float r = 1.f / (1.f + __expf(-(b2f(xr[j]) + b2f(hr[j]))));
        float z = 1.f / (1.f + __expf(-(b2f(xz[j]) + b2f(hz[j]))));
        float n = tanhf(b2f(xn[j]) + r * b2f(hn[j]));
        op[j] = (unsigned short)f2bf((1.f - z) * n + z * mv[j]);
    }
    *(ushort4*)(u + e) = out;
}

// ---------------------------------------------------------------------------
// LayerNorm over rows of 512 (f32 in, f32 out)
// ---------------------------------------------------------------------------
__global__ __launch_bounds__(256) void ln_kernel(
    const float* __restrict__ Y, const float* __restrict__ g,
    const float* __restrict__ be, float* __restrict__ out)
{
    int row = blockIdx.x, t = threadIdx.x;
    const float* yr = Y + (size_t)row * Hh;
    float v0 = yr[t], v1 = yr[t + 256];
    float s = v0 + v1, s2 = v0 * v0 + v1 * v1;
#pragma unroll
    for (int o = 1; o < 64; o <<= 1) {
        s += __shfl_xor(s, o);
        s2 += __shfl_xor(s2, o);
    }
    __shared__ float rs[4], rs2[4];
    int w = t >> 6;
    if ((t & 63) == 0) { rs[w] = s; rs2[w] = s2; }
    __syncthreads();
    float ts = rs[0] + rs[1] + rs[2] + rs[3];
    float ts2 = rs2[0] + rs2[1] + rs2[2] + rs2[3];
    float mu = ts * (1.0f / Hh);
    float var = ts2 * (1.0f / Hh) - mu * mu;
    float rstd = rsqrtf(var + EPSs);
    out[(size_t)row * Hh + t] = (v0 - mu) * rstd * g[t] + be[t];
    out[(size_t)row * Hh + t + 256] = (v1 - mu) * rstd * g[t + 256] + be[t + 256];
}

// ---------------------------------------------------------------------------
extern "C" void kernel_launch(void* const* d_in, const int* in_sizes, int n_in,
                              void* d_out, int out_size, void* d_ws, size_t ws_size,
                              hipStream_t stream) {
    const float* messages = (const float*)d_in[0];
    const float* dist     = (const float*)d_in[1];
    const float* mask     = (const float*)d_in[2];
    const float* emb      = (const float*)d_in[3];
    const float* Wdq = (const float*)d_in[4];  const float* bdq = (const float*)d_in[5];
    const float* Wdk = (const float*)d_in[6];  const float* bdk = (const float*)d_in[7];
    const float* Wq  = (const float*)d_in[8];  const float* bq  = (const float*)d_in[9];
    const float* Wk  = (const float*)d_in[10]; const float* bk  = (const float*)d_in[11];
    const float* Wv  = (const float*)d_in[12]; const float* bv  = (const float*)d_in[13];
    const float* Wo  = (const float*)d_in[14]; const float* bo  = (const float*)d_in[15];
    const float* W_ih = (const float*)d_in[16]; const float* b_ih = (const float*)d_in[17];
    const float* W_hh = (const float*)d_in[18]; const float* b_hh = (const float*)d_in[19];
    const float* W1  = (const float*)d_in[20]; const float* b1  = (const float*)d_in[21];
    const float* W2  = (const float*)d_in[22]; const float* b2  = (const float*)d_in[23];
    const float* g2  = (const float*)d_in[24]; const float* beta2 = (const float*)d_in[25];

    const int M = Bz * Nn;  // 2048
    char* ws = (char*)d_ws;

    // workspace layout (bytes); contiguity required for fused W blocks
    unsigned short* wdqb = (unsigned short*)(ws + 0);         // [512,64]
    unsigned short* wdkb = (unsigned short*)(ws + 65536);     // (wdqb||wdkb)
    unsigned short* wqkv = (unsigned short*)(ws + 131072);    // [1536,512] wq|wk|wv
    unsigned short* wob  = (unsigned short*)(ws + 1703936);   // [512,512]
    unsigned short* wgate= (unsigned short*)(ws + 2228224);   // [3072,512] wih|whh
    unsigned short* w1b  = (unsigned short*)(ws + 5373952);   // [2048,512]
    unsigned short* w2b  = (unsigned short*)(ws + 7471104);   // [512,2048]
    unsigned short* msgs = (unsigned short*)(ws + 9568256);   // [2048,512]
    unsigned short* dqe  = (unsigned short*)(ws + 11665408);  // [2048,64]
    unsigned short* dke  = (unsigned short*)(ws + 11927552);
    unsigned short* XQXK = (unsigned short*)(ws + 12189696);  // [2048,1024]
    unsigned short* QKVb = (unsigned short*)(ws + 16384000);  // [2048,1536]
    unsigned short* AO   = (unsigned short*)(ws + 22675456);  // [2048,512]
    unsigned short* aob  = (unsigned short*)(ws + 24772608);  // [2048,512]
    unsigned short* G    = (unsigned short*)(ws + 26869760);  // [2048,3072]
    unsigned short* ub   = (unsigned short*)(ws + 39452672);  // [2048,512]
    unsigned short* f1   = (unsigned short*)(ws + 41549824);  // [2048,2048]
    float*          yb   = (float*)(ws + 49938432);           // [2048,512] f32
    float*          distT= (float*)(ws + 54132736);           // [4,512,512] f32

    dim3 blk(256);

    // 0) convert weights + messages to bf16  ||  transpose dist
    CvtArgs ca;
    ca.src[0] = messages; ca.dst[0] = msgs; ca.n[0] = M * Hh;
    ca.src[1] = Wdq;  ca.dst[1] = wdqb;          ca.n[1] = Hh * DEe;
    ca.src[2] = Wdk;  ca.dst[2] = wdkb;          ca.n[2] = Hh * DEe;
    ca.src[3] = Wq;   ca.dst[3] = wqkv;          ca.n[3] = Hh * Hh;
    ca.src[4] = Wk;   ca.dst[4] = wqkv + 262144; ca.n[4] = Hh * Hh;
    ca.src[5] = Wv;   ca.dst[5] = wqkv + 524288; ca.n[5] = Hh * Hh;
    ca.src[6] = Wo;   ca.dst[6] = wob;           ca.n[6] = Hh * Hh;
    ca.src[7] = W_ih; ca.dst[7] = wgate;         ca.n[7] = 3 * Hh * Hh;
    ca.src[8] = W_hh; ca.dst[8] = wgate + 786432;ca.n[8] = 3 * Hh * Hh;
    ca.src[9] = W1;   ca.dst[9] = w1b;           ca.n[9] = DFFf * Hh;
    ca.src[10] = W2;  ca.dst[10] = w2b;          ca.n[10] = Hh * DFFf;
    cvttr_kernel<<<768, blk, 0, stream>>>(ca, dist, distT);

    // 1) fused distance-embedding means
    dmean2_kernel<<<dim3(M, 2), blk, 0, stream>>>(dist, distT, emb, dqe, dke);

    // 2) fused XQ|XK = messages + dmean @ Wd^T   (N=1024, K=64)
    {
        SegArgs sa = {};
        sa.A[0] = dqe; sa.A[1] = dke; sa.lda[0] = 64; sa.lda[1] = 64;
        sa.bias[0] = bdq; sa.bias[1] = bdk;
        sa.res[0] = messages; sa.res[1] = messages; sa.rlda = Hh;
        mgf_kernel<128, 64, 0, 1, 0><<<dim3(16, 16), blk, 0, stream>>>(
            sa, wdqb, XQXK, DEe, 512, 1024);
    }

    // 3) fused Q|K|V projections  (N=1536, K=512), 64x128 tiles -> 384 blocks
    {
        SegArgs sa = {};
        sa.A[0] = XQXK; sa.A[1] = XQXK + 512; sa.A[2] = msgs;
        sa.lda[0] = 1024; sa.lda[1] = 1024; sa.lda[2] = 512;
        sa.bias[0] = bq; sa.bias[1] = bk; sa.bias[2] = bv;
        mgf_kernel<64, 128, 0, 0, 0><<<dim3(12, 32), blk, 0, stream>>>(
            sa, wqkv, QKVb, Hh, 512, QS);
    }

    // 4) attention
    attn_mfma_kernel<<<dim3(Nn / 64, NHh, Bz), blk, 0, stream>>>(
        QKVb, mask, AO);

    // 5) output projection (64x64 tiles -> 256 blocks)
    {
        SegArgs sa = {};
        sa.A[0] = AO; sa.lda[0] = 512; sa.bias[0] = bo;
        mgf_kernel<64, 64, 0, 0, 0><<<dim3(8, 32), blk, 0, stream>>>(
            sa, wob, aob, Hh, 512, 512);
    }

    // 6) fused GRU gates gx|gh  (N=3072, K=512), then elementwise
    {
        SegArgs sa = {};
        sa.A[0] = aob; sa.A[1] = msgs; sa.lda[0] = 512; sa.lda[1] = 512;
        sa.bias[0] = b_ih; sa.bias[1] = b_hh;
        mgf_kernel<128, 128, 0, 0, 0><<<dim3(24, 16), blk, 0, stream>>>(
            sa, wgate, G, Hh, 1536, GS);
    }
    gru_kernel<<<(M * Hh) / 1024, blk, 0, stream>>>(G, messages, ub);

    // 7) FFN
    {
        SegArgs sa = {};
        sa.A[0] = ub; sa.lda[0] = 512; sa.bias[0] = b1;
        mgf_kernel<128, 128, 1, 0, 0><<<dim3(16, 16), blk, 0, stream>>>(
            sa, w1b, f1, Hh, 2048, DFFf);
    }
    {
        SegArgs sa = {};
        sa.A[0] = f1; sa.lda[0] = 2048; sa.bias[0] = b2;
        sa.res[0] = ub; sa.rlda = 512;
        mgf_kernel<64, 64, 0, 2, 1><<<dim3(8, 32), blk, 0, stream>>>(
            sa, w2b, yb, DFFf, 512, 512);
    }

    // 8) LayerNorm -> out
    ln_kernel<<<M, blk, 0, stream>>>(yb, g2, beta2, (float*)d_out);
}

// Round 8
// 123.528 us; speedup vs baseline: 2.9582x; 1.1707x over previous
//
#include <hip/hip_runtime.h>
#include <hip/hip_bf16.h>
#include <math.h>

#define Bz 4
#define Nn 512
#define Hh 512
#define NHh 8
#define HDd 64
#define DEe 64
#define DFFf 2048
#define EPSs 1e-5f
#define QS 1536      // fused QKV row stride
#define GS 3072      // fused gate row stride

typedef __attribute__((ext_vector_type(8))) short bf16x8;
typedef __attribute__((ext_vector_type(4))) short bf16x4;
typedef __attribute__((ext_vector_type(4))) float f32x4;

__device__ inline short f2bf(float x) {
    unsigned u = __builtin_bit_cast(unsigned, x);
    unsigned r = (u + 0x7FFFu + ((u >> 16) & 1u)) >> 16;
    return (short)r;
}
__device__ inline float b2f(unsigned short u) {
    unsigned v = ((unsigned)u) << 16;
    return __builtin_bit_cast(float, v);
}
__device__ inline void gld16(const void* g, void* l) {
    __builtin_amdgcn_global_load_lds(
        (const __attribute__((address_space(1))) void*)g,
        (__attribute__((address_space(3))) void*)l, 16, 0, 0);
}

// ---------------------------------------------------------------------------
// Merged: segmented f32->bf16 conversion (blocks 0..511, incl. emb/512
// zero-padded to 256 bins) + dist transpose (blocks 512..767).
// ---------------------------------------------------------------------------
struct CvtArgs {
    const float* src[11];
    unsigned short* dst[11];
    int n[11];
};
__global__ __launch_bounds__(256) void cvttr_kernel(
    CvtArgs a, const float* __restrict__ dist, float* __restrict__ distT,
    const float* __restrict__ emb, unsigned short* __restrict__ embb)
{
    __shared__ float T[64][68];
    int t = threadIdx.x;
    if (blockIdx.x < 512) {
        for (int sg = 0; sg < 11; ++sg) {
            const float4* s = (const float4*)a.src[sg];
            ushort4* d = (ushort4*)a.dst[sg];
            int n4 = a.n[sg] >> 2;
            for (int i = blockIdx.x * 256 + t; i < n4; i += 512 * 256) {
                float4 v = s[i];
                ushort4 o = {(unsigned short)f2bf(v.x), (unsigned short)f2bf(v.y),
                             (unsigned short)f2bf(v.z), (unsigned short)f2bf(v.w)};
                d[i] = o;
            }
        }
        // embb = emb * (1/512), rows 201..255 zero  (256*64 elems, src 201*64)
        const float sc = 1.0f / 512.0f;
        for (int i = blockIdx.x * 256 + t; i < 4096; i += 512 * 256) {
            ushort4 o = {0, 0, 0, 0};
            if (i * 4 < 201 * 64) {
                float4 v = *(const float4*)(emb + i * 4);
                o.x = (unsigned short)f2bf(v.x * sc);
                o.y = (unsigned short)f2bf(v.y * sc);
                o.z = (unsigned short)f2bf(v.z * sc);
                o.w = (unsigned short)f2bf(v.w * sc);
            }
            *(ushort4*)(embb + i * 4) = o;
        }
    } else {
        int tid = blockIdx.x - 512;           // 0..255
        int b = tid >> 6;
        int i0 = ((tid >> 3) & 7) * 64, j0 = (tid & 7) * 64;
        int rr = t >> 4, c4 = (t & 15) * 4;
#pragma unroll
        for (int p = 0; p < 4; ++p) {
            int r = rr + p * 16;
            float4 v = *(const float4*)&dist[((size_t)(b * Nn + i0 + r)) * Nn + j0 + c4];
            *(float4*)&T[r][c4] = v;
        }
        __syncthreads();
#pragma unroll
        for (int p = 0; p < 4; ++p) {
            int jr = rr + p * 16;
            float4 v = {T[c4 + 0][jr], T[c4 + 1][jr], T[c4 + 2][jr], T[c4 + 3][jr]};
            *(float4*)&distT[((size_t)(b * Nn + j0 + jr)) * Nn + i0 + c4] = v;
        }
    }
}

// ---------------------------------------------------------------------------
// Per-row 201-bin histogram of dist (y=0) / distT (y=1), bf16 counts,
// padded to 256 bins. Counts <= 512 are bf16-exact up to 256 (and 512).
// ---------------------------------------------------------------------------
__global__ __launch_bounds__(256) void hist2_kernel(
    const float* __restrict__ dist, const float* __restrict__ distT,
    unsigned short* __restrict__ histq, unsigned short* __restrict__ histk)
{
    __shared__ int hist[256];
    int bi = blockIdx.x;
    const float* src = blockIdx.y ? distT : dist;
    unsigned short* out = blockIdx.y ? histk : histq;
    int t = threadIdx.x;
    hist[t] = 0;
    __syncthreads();
    float2 v = *(const float2*)(src + (size_t)bi * Nn + t * 2);
    int i0 = min(max((int)v.x, 0), 200);
    int i1 = min(max((int)v.y, 0), 200);
    atomicAdd(&hist[i0], 1);
    atomicAdd(&hist[i1], 1);
    __syncthreads();
    out[(size_t)bi * 256 + t] = (unsigned short)f2bf((float)hist[t]);
}

// ---------------------------------------------------------------------------
// Fused bf16 MFMA GEMM, up to 3 N-segments, LDS double-buffered 2-phase.
// RESM: 0 none, 1 f32 residual, 2 bf16 residual. OUTF: 1 f32 out, 0 bf16.
// HASB: 0 = no bias.
// ---------------------------------------------------------------------------
struct SegArgs {
    const unsigned short* A[3];
    int lda[3];
    const float* bias[3];
    const void* res[3];
    int rlda;
};

template<int BM, int BN, int RELU, int RESM, int OUTF, int HASB>
__global__ __launch_bounds__(256) void mgf_kernel(
    SegArgs sa, const unsigned short* __restrict__ W,
    void* __restrict__ C, int K, int SW, int ldc)
{
    constexpr int WM = BM / 2, WN = BN / 2;
    constexpr int MT = WM / 16, NT = WN / 16;
    constexpr int IPA = BM / 32, IPB = BN / 32;
    __shared__ unsigned short As[2][BM * 64];
    __shared__ unsigned short Bs[2][BN * 64];
    int t = threadIdx.x, lane = t & 63, wid = t >> 6;
    int wm = wid >> 1, wn = wid & 1;
    int m0 = blockIdx.y * BM, n0 = blockIdx.x * BN;
    int seg = n0 / SW;
    int segbase = seg * SW;
    const unsigned short* A = sa.A[seg];
    int lda = sa.lda[seg];
    int lrow8 = lane >> 3;
    int lunit = (lane & 7) ^ lrow8;     // inverse-swizzled source unit

    f32x4 acc[MT][NT] = {};

    auto stage = [&](int buf, int kt) {
#pragma unroll
        for (int i = 0; i < IPA; ++i) {
            int c = wid * IPA + i;
            gld16(A + (size_t)(m0 + c * 8 + lrow8) * lda + kt + lunit * 8,
                  &As[buf][c * 512]);
        }
#pragma unroll
        for (int i = 0; i < IPB; ++i) {
            int c = wid * IPB + i;
            gld16(W + (size_t)(n0 + c * 8 + lrow8) * K + kt + lunit * 8,
                  &Bs[buf][c * 512]);
        }
    };

    stage(0, 0);
    __syncthreads();
    int cur = 0;
    for (int kt = 0; kt < K; kt += 64) {
        if (kt + 64 < K) stage(cur ^ 1, kt + 64);
#pragma unroll
        for (int kk = 0; kk < 2; ++kk) {
            bf16x8 fa[MT], fb[NT];
            int ub = kk * 4 + (lane >> 4);
#pragma unroll
            for (int mt = 0; mt < MT; ++mt) {
                int r = wm * WM + mt * 16 + (lane & 15);
                fa[mt] = *(const bf16x8*)&As[cur][r * 64 + ((ub ^ (r & 7)) << 3)];
            }
#pragma unroll
            for (int nt = 0; nt < NT; ++nt) {
                int r = wn * WN + nt * 16 + (lane & 15);
                fb[nt] = *(const bf16x8*)&Bs[cur][r * 64 + ((ub ^ (r & 7)) << 3)];
            }
#pragma unroll
            for (int mt = 0; mt < MT; ++mt)
#pragma unroll
                for (int nt = 0; nt < NT; ++nt)
                    acc[mt][nt] = __builtin_amdgcn_mfma_f32_16x16x32_bf16(
                        fa[mt], fb[nt], acc[mt][nt], 0, 0, 0);
        }
        __syncthreads();    // drains this iter's gld16 + joins waves
        cur ^= 1;
    }

    int cr = (lane >> 4) * 4, ccl = lane & 15;
#pragma unroll
    for (int mt = 0; mt < MT; ++mt) {
#pragma unroll
        for (int nt = 0; nt < NT; ++nt) {
            int col = n0 + wn * WN + nt * 16 + ccl;
            int lcol = col - segbase;
            float bv = HASB ? sa.bias[seg][lcol] : 0.f;
#pragma unroll
            for (int r = 0; r < 4; ++r) {
                int row = m0 + wm * WM + mt * 16 + cr + r;
                float o = acc[mt][nt][r] + bv;
                if (RESM == 1)
                    o += ((const float*)sa.res[seg])[(size_t)row * sa.rlda + lcol];
                if (RESM == 2)
                    o += b2f(((const unsigned short*)sa.res[seg])
                                 [(size_t)row * sa.rlda + lcol]);
                if (RELU) o = fmaxf(o, 0.f);
                if (OUTF)
                    ((float*)C)[(size_t)row * ldc + col] = o;
                else
                    ((unsigned short*)C)[(size_t)row * ldc + col] =
                        (unsigned short)f2bf(o);
            }
        }
    }
}

// ---------------------------------------------------------------------------
// MFMA flash attention reading fused QKV [M, 1536] (Q +0, K +512, V +1024).
// One block per (b, h, 64 q-rows); swapped QK^T; online softmax; O^T=V^T@P^T.
// ---------------------------------------------------------------------------
__global__ __launch_bounds__(256) void attn_mfma_kernel(
    const unsigned short* __restrict__ QKV, const float* __restrict__ mask,
    unsigned short* __restrict__ AO)
{
    __shared__ unsigned short Qs[64 * 64];
    __shared__ unsigned short Ks[64 * 64];
    __shared__ unsigned short Vt[64 * 64];
    __shared__ float Ms[64 * 65];
    __shared__ unsigned short Pl[4][16 * 72];

    int t = threadIdx.x;
    int lane = t & 63;
    int wq = t >> 6;
    int g = lane >> 4, cc = lane & 15;
    int q0 = blockIdx.x * 64;
    int h = blockIdx.y, b = blockIdx.z;

    int lr = t >> 2;
    int u0 = (t & 3) * 2;
    int c0f = (t & 3) * 16;

    // ---- stage Q once ----
    {
        const unsigned short* src =
            QKV + ((size_t)(b * Nn + q0 + lr)) * QS + h * HDd + u0 * 8;
        bf16x8 p0 = *(const bf16x8*)(src);
        bf16x8 p1 = *(const bf16x8*)(src + 8);
        *(bf16x8*)&Qs[lr * 64 + ((u0 ^ (lr & 7)) << 3)] = p0;
        *(bf16x8*)&Qs[lr * 64 + (((u0 + 1) ^ (lr & 7)) << 3)] = p1;
    }

    const unsigned short* Krow =
        QKV + ((size_t)(b * Nn + lr)) * QS + 512 + h * HDd + u0 * 8;
    int vkey = t >> 4;
    int vd0 = (t & 15) * 4;
    const unsigned short* Vbase =
        QKV + ((size_t)(b * Nn)) * QS + 1024 + h * HDd + vd0;
    const float* Mrow = mask + ((size_t)(b * Nn + q0 + lr)) * Nn + c0f;

    bf16x8 kr0, kr1;
    ushort4 vr[4];
    float4 mreg[4];
    auto issue = [&](int kc) {
        int k0 = kc * 64;
        const unsigned short* kp = Krow + (size_t)k0 * QS;
        kr0 = *(const bf16x8*)(kp);
        kr1 = *(const bf16x8*)(kp + 8);
        const float* mp = Mrow + k0;
        mreg[0] = *(const float4*)(mp);
        mreg[1] = *(const float4*)(mp + 4);
        mreg[2] = *(const float4*)(mp + 8);
        mreg[3] = *(const float4*)(mp + 12);
#pragma unroll
        for (int p = 0; p < 4; ++p)
            vr[p] = *(const ushort4*)(Vbase + (size_t)(k0 + vkey + p * 16) * QS);
    };
    issue(0);
    __syncthreads();

    bf16x8 qf0 = *(bf16x8*)&Qs[(wq * 16 + cc) * 64 + (((0 * 4 + g) ^ (cc & 7)) << 3)];
    bf16x8 qf1 = *(bf16x8*)&Qs[(wq * 16 + cc) * 64 + (((1 * 4 + g) ^ (cc & 7)) << 3)];

    const float scale = 0.125f;
    float m_run = -1e30f, l_run = 0.f;
    f32x4 o[4] = {};

    for (int kc = 0; kc < 8; ++kc) {
        {
            *(bf16x8*)&Ks[lr * 64 + ((u0 ^ (lr & 7)) << 3)] = kr0;
            *(bf16x8*)&Ks[lr * 64 + (((u0 + 1) ^ (lr & 7)) << 3)] = kr1;

            float* msr = &Ms[lr * 65 + c0f];
            msr[0] = mreg[0].x;  msr[1] = mreg[0].y;  msr[2] = mreg[0].z;  msr[3] = mreg[0].w;
            msr[4] = mreg[1].x;  msr[5] = mreg[1].y;  msr[6] = mreg[1].z;  msr[7] = mreg[1].w;
            msr[8] = mreg[2].x;  msr[9] = mreg[2].y;  msr[10] = mreg[2].z; msr[11] = mreg[2].w;
            msr[12] = mreg[3].x; msr[13] = mreg[3].y; msr[14] = mreg[3].z; msr[15] = mreg[3].w;

#pragma unroll
            for (int p = 0; p < 4; ++p) {
                int key = vkey + p * 16;
                unsigned short vals[4] = {vr[p].x, vr[p].y, vr[p].z, vr[p].w};
#pragma unroll
                for (int jj = 0; jj < 4; ++jj) {
                    int j = (jj + (t >> 2)) & 3;
                    int d = vd0 + j;
                    Vt[d * 64 + (key ^ ((d & 7) << 3))] = vals[j];
                }
            }
        }
        __syncthreads();
        if (kc < 7) issue(kc + 1);

        // ---- QK^T (swapped) ----
        f32x4 s[4] = {};
        __builtin_amdgcn_s_setprio(1);
#pragma unroll
        for (int kt = 0; kt < 4; ++kt) {
            int rA = kt * 16 + cc;
            bf16x8 a0 = *(bf16x8*)&Ks[rA * 64 + (((0 * 4 + g) ^ (rA & 7)) << 3)];
            s[kt] = __builtin_amdgcn_mfma_f32_16x16x32_bf16(a0, qf0, s[kt], 0, 0, 0);
            bf16x8 a1 = *(bf16x8*)&Ks[rA * 64 + (((1 * 4 + g) ^ (rA & 7)) << 3)];
            s[kt] = __builtin_amdgcn_mfma_f32_16x16x32_bf16(a1, qf1, s[kt], 0, 0, 0);
        }
        __builtin_amdgcn_s_setprio(0);

        // ---- mask + online softmax ----
        float pv[4][4];
        float tmax = -1e30f;
#pragma unroll
        for (int kt = 0; kt < 4; ++kt) {
#pragma unroll
            for (int r = 0; r < 4; ++r) {
                float mv = Ms[(wq * 16 + cc) * 65 + kt * 16 + g * 4 + r];
                float svv = (mv == 0.f) ? -1e30f : s[kt][r];
                pv[kt][r] = svv;
                tmax = fmaxf(tmax, svv);
            }
        }
        tmax = fmaxf(tmax, __shfl_xor(tmax, 16));
        tmax = fmaxf(tmax, __shfl_xor(tmax, 32));
        float mnew = fmaxf(m_run, tmax);
        float rescale = __expf((m_run - mnew) * scale);
        float psum = 0.f;
#pragma unroll
        for (int kt = 0; kt < 4; ++kt) {
#pragma unroll
            for (int r = 0; r < 4; ++r) {
                float sv = pv[kt][r];
                float p = (sv == -1e30f) ? 0.f : __expf((sv - mnew) * scale);
                pv[kt][r] = p;
                psum += p;
            }
        }
        psum += __shfl_xor(psum, 16);
        psum += __shfl_xor(psum, 32);
        l_run = l_run * rescale + psum;
        m_run = mnew;
#pragma unroll
        for (int dt = 0; dt < 4; ++dt) {
            o[dt][0] *= rescale; o[dt][1] *= rescale;
            o[dt][2] *= rescale; o[dt][3] *= rescale;
        }

        // ---- P^T bounce through per-wave LDS ----
#pragma unroll
        for (int kt = 0; kt < 4; ++kt) {
            bf16x4 pk = {f2bf(pv[kt][0]), f2bf(pv[kt][1]),
                         f2bf(pv[kt][2]), f2bf(pv[kt][3])};
            *(bf16x4*)&Pl[wq][cc * 72 + kt * 16 + g * 4] = pk;
        }
        bf16x8 pf0 = *(bf16x8*)&Pl[wq][cc * 72 + 0 + g * 8];
        bf16x8 pf1 = *(bf16x8*)&Pl[wq][cc * 72 + 32 + g * 8];

        // ---- PV ----
        __builtin_amdgcn_s_setprio(1);
#pragma unroll
        for (int dt = 0; dt < 4; ++dt) {
            int rV = dt * 16 + cc;
            bf16x8 vf0 = *(bf16x8*)&Vt[rV * 64 + (((0 * 4 + g) ^ (rV & 7)) << 3)];
            o[dt] = __builtin_amdgcn_mfma_f32_16x16x32_bf16(vf0, pf0, o[dt], 0, 0, 0);
            bf16x8 vf1 = *(bf16x8*)&Vt[rV * 64 + (((1 * 4 + g) ^ (rV & 7)) << 3)];
            o[dt] = __builtin_amdgcn_mfma_f32_16x16x32_bf16(vf1, pf1, o[dt], 0, 0, 0);
        }
        __builtin_amdgcn_s_setprio(0);
        __syncthreads();
    }

    float invl = 1.f / l_run;
#pragma unroll
    for (int dt = 0; dt < 4; ++dt) {
        ushort4 w = {(unsigned short)f2bf(o[dt][0] * invl),
                     (unsigned short)f2bf(o[dt][1] * invl),
                     (unsigned short)f2bf(o[dt][2] * invl),
                     (unsigned short)f2bf(o[dt][3] * invl)};
        *(ushort4*)&AO[((size_t)(b * Nn + q0 + wq * 16 + cc)) * Hh +
                       h * HDd + dt * 16 + g * 4] = w;
    }
}

// ---------------------------------------------------------------------------
// GRU elementwise reading fused gate buffer G [M, 3072] (gx +0, gh +1536)
// ---------------------------------------------------------------------------
__global__ __launch_bounds__(256) void gru_kernel(
    const unsigned short* __restrict__ G,
    const float* __restrict__ msg, unsigned short* __restrict__ u)
{
    int i4 = blockIdx.x * 256 + threadIdx.x;
    int e = i4 * 4;
    int row = e >> 9, col = e & 511;
    const unsigned short* gxr = G + (size_t)row * GS;
    const unsigned short* ghr = gxr + 1536;
    ushort4 xr4 = *(const ushort4*)(gxr + col);
    ushort4 xz4 = *(const ushort4*)(gxr + col + 512);
    ushort4 xn4 = *(const ushort4*)(gxr + col + 1024);
    ushort4 hr4 = *(const ushort4*)(ghr + col);
    ushort4 hz4 = *(const ushort4*)(ghr + col + 512);
    ushort4 hn4 = *(const ushort4*)(ghr + col + 1024);
    float4 mg4 = *(const float4*)(msg + e);
    float mv[4] = {mg4.x, mg4.y, mg4.z, mg4.w};
    unsigned short xr[4] = {xr4.x, xr4.y, xr4.z, xr4.w};
    unsigned short xz[4] = {xz4.x, xz4.y, xz4.z, xz4.w};
    unsigned short xn[4] = {xn4.x, xn4.y, xn4.z, xn4.w};
    unsigned short hr[4] = {hr4.x, hr4.y, hr4.z, hr4.w};
    unsigned short hz[4] = {hz4.x, hz4.y, hz4.z, hz4.w};
    unsigned short hn[4] = {hn4.x, hn4.y, hn4.z, hn4.w};
    ushort4 out;
    unsigned short* op = (unsigned short*)&out;
#pragma unroll
    for (int j = 0; j < 4; ++j) {
        float r = 1.f / (1.f + __expf(-(b2f(xr[j]) + b2f(hr[j]))));
        float z = 1.f / (1.f + __expf(-(b2f(xz[j]) + b2f(hz[j]))));
        float n = tanhf(b2f(xn[j]) + r * b2f(hn[j]));
        op[j] = (unsigned short)f2bf((1.f - z) * n + z * mv[j]);
    }
    *(ushort4*)(u + e) = out;
}

// ---------------------------------------------------------------------------
// LayerNorm over rows of 512 (f32 in, f32 out)
// ---------------------------------------------------------------------------
__global__ __launch_bounds__(256) void ln_kernel(
    const float* __restrict__ Y, const float* __restrict__ g,
    const float* __restrict__ be, float* __restrict__ out)
{
    int row = blockIdx.x, t = threadIdx.x;
    const float* yr = Y + (size_t)row * Hh;
    float v0 = yr[t], v1 = yr[t + 256];
    float s = v0 + v1, s2 = v0 * v0 + v1 * v1;
#pragma unroll
    for (int o = 1; o < 64; o <<= 1) {
        s += __shfl_xor(s, o);
        s2 += __shfl_xor(s2, o);
    }
    __shared__ float rs[4], rs2[4];
    int w = t >> 6;
    if ((t & 63) == 0) { rs[w] = s; rs2[w] = s2; }
    __syncthreads();
    float ts = rs[0] + rs[1] + rs[2] + rs[3];
    float ts2 = rs2[0] + rs2[1] + rs2[2] + rs2[3];
    float mu = ts * (1.0f / Hh);
    float var = ts2 * (1.0f / Hh) - mu * mu;
    float rstd = rsqrtf(var + EPSs);
    out[(size_t)row * Hh + t] = (v0 - mu) * rstd * g[t] + be[t];
    out[(size_t)row * Hh + t + 256] = (v1 - mu) * rstd * g[t + 256] + be[t + 256];
}

// ---------------------------------------------------------------------------
extern "C" void kernel_launch(void* const* d_in, const int* in_sizes, int n_in,
                              void* d_out, int out_size, void* d_ws, size_t ws_size,
                              hipStream_t stream) {
    const float* messages = (const float*)d_in[0];
    const float* dist     = (const float*)d_in[1];
    const float* mask     = (const float*)d_in[2];
    const float* emb      = (const float*)d_in[3];
    const float* Wdq = (const float*)d_in[4];  const float* bdq = (const float*)d_in[5];
    const float* Wdk = (const float*)d_in[6];  const float* bdk = (const float*)d_in[7];
    const float* Wq  = (const float*)d_in[8];  const float* bq  = (const float*)d_in[9];
    const float* Wk  = (const float*)d_in[10]; const float* bk  = (const float*)d_in[11];
    const float* Wv  = (const float*)d_in[12]; const float* bv  = (const float*)d_in[13];
    const float* Wo  = (const float*)d_in[14]; const float* bo  = (const float*)d_in[15];
    const float* W_ih = (const float*)d_in[16]; const float* b_ih = (const float*)d_in[17];
    const float* W_hh = (const float*)d_in[18]; const float* b_hh = (const float*)d_in[19];
    const float* W1  = (const float*)d_in[20]; const float* b1  = (const float*)d_in[21];
    const float* W2  = (const float*)d_in[22]; const float* b2  = (const float*)d_in[23];
    const float* g2  = (const float*)d_in[24]; const float* beta2 = (const float*)d_in[25];

    const int M = Bz * Nn;  // 2048
    char* ws = (char*)d_ws;

    // workspace layout (bytes); contiguity required for fused W blocks
    unsigned short* wdqb = (unsigned short*)(ws + 0);         // [512,64]
    unsigned short* wdkb = (unsigned short*)(ws + 65536);     // (wdqb||wdkb = [1024,64])
    unsigned short* wqkv = (unsigned short*)(ws + 131072);    // [1536,512] wq|wk|wv
    unsigned short* wob  = (unsigned short*)(ws + 1703936);   // [512,512]
    unsigned short* wgate= (unsigned short*)(ws + 2228224);   // [3072,512] wih|whh
    unsigned short* w1b  = (unsigned short*)(ws + 5373952);   // [2048,512]
    unsigned short* w2b  = (unsigned short*)(ws + 7471104);   // [512,2048]
    unsigned short* msgs = (unsigned short*)(ws + 9568256);   // [2048,512]
    unsigned short* XQXK = (unsigned short*)(ws + 12189696);  // [2048,1024]
    unsigned short* QKVb = (unsigned short*)(ws + 16384000);  // [2048,1536]
    unsigned short* AO   = (unsigned short*)(ws + 22675456);  // [2048,512]
    unsigned short* aob  = (unsigned short*)(ws + 24772608);  // [2048,512]
    unsigned short* G    = (unsigned short*)(ws + 26869760);  // [2048,3072]
    unsigned short* ub   = (unsigned short*)(ws + 39452672);  // [2048,512]
    unsigned short* f1   = (unsigned short*)(ws + 41549824);  // [2048,2048]
    float*          yb   = (float*)(ws + 49938432);           // [2048,512] f32
    float*          distT= (float*)(ws + 54132736);           // [4,512,512] f32
    unsigned short* embb = (unsigned short*)(ws + 58327040);  // [256,64] emb/512 padded
    unsigned short* histq= (unsigned short*)(ws + 58359808);  // [2048,256]
    unsigned short* histk= (unsigned short*)(ws + 59408384);  // [2048,256]
    unsigned short* Ecat = (unsigned short*)(ws + 60456960);  // [1024,256] Eq^T|Ek^T

    dim3 blk(256);

    // 0) convert weights + messages to bf16 || emb/512 padded || transpose dist
    CvtArgs ca;
    ca.src[0] = messages; ca.dst[0] = msgs; ca.n[0] = M * Hh;
    ca.src[1] = Wdq;  ca.dst[1] = wdqb;          ca.n[1] = Hh * DEe;
    ca.src[2] = Wdk;  ca.dst[2] = wdkb;          ca.n[2] = Hh * DEe;
    ca.src[3] = Wq;   ca.dst[3] = wqkv;          ca.n[3] = Hh * Hh;
    ca.src[4] = Wk;   ca.dst[4] = wqkv + 262144; ca.n[4] = Hh * Hh;
    ca.src[5] = Wv;   ca.dst[5] = wqkv + 524288; ca.n[5] = Hh * Hh;
    ca.src[6] = Wo;   ca.dst[6] = wob;           ca.n[6] = Hh * Hh;
    ca.src[7] = W_ih; ca.dst[7] = wgate;         ca.n[7] = 3 * Hh * Hh;
    ca.src[8] = W_hh; ca.dst[8] = wgate + 786432;ca.n[8] = 3 * Hh * Hh;
    ca.src[9] = W1;   ca.dst[9] = w1b;           ca.n[9] = DFFf * Hh;
    ca.src[10] = W2;  ca.dst[10] = w2b;          ca.n[10] = Hh * DFFf;
    cvttr_kernel<<<768, blk, 0, stream>>>(ca, dist, distT, emb, embb);

    // 1) per-row histograms of dist / distT (bf16 counts, 256 bins)
    hist2_kernel<<<dim3(M, 2), blk, 0, stream>>>(dist, distT, histq, histk);

    // 1b) Ecat = (Wdq|Wdk) @ embb^T   [1024,256], no bias
    {
        SegArgs sa = {};
        sa.A[0] = wdqb; sa.lda[0] = 64;
        mgf_kernel<128, 64, 0, 0, 0, 0><<<dim3(4, 8), blk, 0, stream>>>(
            sa, embb, Ecat, 64, 256, 256);
    }

    // 2) fused XQ|XK = messages + hist @ Ecat^T + bias   (N=1024, K=256)
    {
        SegArgs sa = {};
        sa.A[0] = histq; sa.A[1] = histk; sa.lda[0] = 256; sa.lda[1] = 256;
        sa.bias[0] = bdq; sa.bias[1] = bdk;
        sa.res[0] = messages; sa.res[1] = messages; sa.rlda = Hh;
        mgf_kernel<128, 64, 0, 1, 0, 1><<<dim3(16, 16), blk, 0, stream>>>(
            sa, Ecat, XQXK, 256, 512, 1024);
    }

    // 3) fused Q|K|V projections  (N=1536, K=512), 64x128 tiles -> 384 blocks
    {
        SegArgs sa = {};
        sa.A[0] = XQXK; sa.A[1] = XQXK + 512; sa.A[2] = msgs;
        sa.lda[0] = 1024; sa.lda[1] = 1024; sa.lda[2] = 512;
        sa.bias[0] = bq; sa.bias[1] = bk; sa.bias[2] = bv;
        mgf_kernel<64, 128, 0, 0, 0, 1><<<dim3(12, 32), blk, 0, stream>>>(
            sa, wqkv, QKVb, Hh, 512, QS);
    }

    // 4) attention
    attn_mfma_kernel<<<dim3(Nn / 64, NHh, Bz), blk, 0, stream>>>(
        QKVb, mask, AO);

    // 5) output projection (64x64 tiles -> 256 blocks)
    {
        SegArgs sa = {};
        sa.A[0] = AO; sa.lda[0] = 512; sa.bias[0] = bo;
        mgf_kernel<64, 64, 0, 0, 0, 1><<<dim3(8, 32), blk, 0, stream>>>(
            sa, wob, aob, Hh, 512, 512);
    }

    // 6) fused GRU gates gx|gh  (N=3072, K=512), then elementwise
    {
        SegArgs sa = {};
        sa.A[0] = aob; sa.A[1] = msgs; sa.lda[0] = 512; sa.lda[1] = 512;
        sa.bias[0] = b_ih; sa.bias[1] = b_hh;
        mgf_kernel<128, 128, 0, 0, 0, 1><<<dim3(24, 16), blk, 0, stream>>>(
            sa, wgate, G, Hh, 1536, GS);
    }
    gru_kernel<<<(M * Hh) / 1024, blk, 0, stream>>>(G, messages, ub);

    // 7) FFN
    {
        SegArgs sa = {};
        sa.A[0] = ub; sa.lda[0] = 512; sa.bias[0] = b1;
        mgf_kernel<128, 128, 1, 0, 0, 1><<<dim3(16, 16), blk, 0, stream>>>(
            sa, w1b, f1, Hh, 2048, DFFf);
    }
    {
        SegArgs sa = {};
        sa.A[0] = f1; sa.lda[0] = 2048; sa.bias[0] = b2;
        sa.res[0] = ub; sa.rlda = 512;
        mgf_kernel<64, 64, 0, 2, 1, 1><<<dim3(8, 32), blk, 0, stream>>>(
            sa, w2b, yb, DFFf, 512, 512);
    }

    // 8) LayerNorm -> out
    ln_kernel<<<M, blk, 0, stream>>>(yb, g2, beta2, (float*)d_out);
}